// Round 6
// baseline (275.791 us; speedup 1.0000x reference)
//
#include <hip/hip_runtime.h>

typedef __bf16 bf16_t;
typedef __bf16 bf16x4 __attribute__((ext_vector_type(4)));
typedef __bf16 bf16x8 __attribute__((ext_vector_type(8)));
typedef float  f32x4  __attribute__((ext_vector_type(4)));

#define MFMA(a, b, c) __builtin_amdgcn_mfma_f32_16x16x32_bf16((a), (b), (c), 0, 0, 0)

static constexpr int Bsz = 2, S = 2048, D = 1024, H = 16, DK = 64;
// softmax runs in exp2 domain: Q is pre-scaled by 0.125 * log2(e)
#define QSCALE 0.18033688011112042f

// ---------------------------------------------------------------------------
// One-pass f32 -> bf16 conversion of x, z, wq, wk, wo. Each thread converts
// one float4. Segment boundaries are multiples of 64 -> wave-uniform branches.
// ---------------------------------------------------------------------------
__global__ __launch_bounds__(256) void cvt5(
    const float* __restrict__ x, const float* __restrict__ z,
    const float* __restrict__ wq, const float* __restrict__ wk,
    const float* __restrict__ wo,
    bf16_t* __restrict__ xb, bf16_t* __restrict__ zb,
    bf16_t* __restrict__ wqb, bf16_t* __restrict__ wkb, bf16_t* __restrict__ wob)
{
    constexpr int NXZ = Bsz * S * D / 4;   // 1,048,576 float4 chunks
    constexpr int NW  = D * D / 4;         //   262,144
    int i = blockIdx.x * 256 + threadIdx.x;
    const float* s; bf16_t* d; int off;
    if (i < NXZ)                 { s = x;  d = xb;  off = i; }
    else if (i < 2 * NXZ)        { s = z;  d = zb;  off = i - NXZ; }
    else if (i < 2 * NXZ + NW)   { s = wq; d = wqb; off = i - 2 * NXZ; }
    else if (i < 2 * NXZ + 2*NW) { s = wk; d = wkb; off = i - 2 * NXZ - NW; }
    else                         { s = wo; d = wob; off = i - 2 * NXZ - 2 * NW; }
    float4 v = *(const float4*)&s[(size_t)off * 4];
    bf16x4 o;
    o[0] = (bf16_t)v.x; o[1] = (bf16_t)v.y; o[2] = (bf16_t)v.z; o[3] = (bf16_t)v.w;
    *(bf16x4*)&d[(size_t)off * 4] = o;
}

// ---------------------------------------------------------------------------
// Fused Q/K projection, all-bf16 operands. blockIdx.z selects
// (xb,wqb)->Q*QSCALE or (zb,wkb)->K + KT. 128x128 tile, BK=32, 512 threads
// (8 waves, 4x2 of 32x64), register-prefetch dbuf LDS, 1 barrier/K-step.
// ---------------------------------------------------------------------------
__global__ __launch_bounds__(512) void gemm_qk(
    const bf16_t* __restrict__ xA, const bf16_t* __restrict__ wqB,
    const float* __restrict__ wqb, bf16_t* __restrict__ Qc,
    const bf16_t* __restrict__ zA, const bf16_t* __restrict__ wkB,
    const float* __restrict__ wkb, bf16_t* __restrict__ Kc,
    bf16_t* __restrict__ KTout)
{
    constexpr int N = D, K = D;
    const int zi = blockIdx.z;
    const bf16_t* A    = zi ? zA  : xA;
    const bf16_t* B    = zi ? wkB : wqB;
    const float*  bias = zi ? wkb : wqb;
    bf16_t*       C    = zi ? Kc  : Qc;
    const float   sc   = zi ? 1.f : QSCALE;   // fold softmax scale + log2e into Q

    __shared__ bf16_t As[2][128][40];
    __shared__ bf16_t Bs[2][128][40];

    const int t    = threadIdx.x;
    const int wave = t >> 6, lane = t & 63;
    const int quad = lane >> 4, l15 = lane & 15;
    const int wm = (wave >> 1) * 32, wn = (wave & 1) * 64;
    const int rowbase = blockIdx.y * 128, colbase = blockIdx.x * 128;
    const int r  = t >> 2;            // staging row 0..127
    const int cc = (t & 3) << 3;      // staging col 0,8,16,24

    f32x4 acc[2][4];
#pragma unroll
    for (int i = 0; i < 2; ++i)
#pragma unroll
        for (int j = 0; j < 4; ++j) acc[i][j] = {0.f, 0.f, 0.f, 0.f};

    bf16x8 areg = *(const bf16x8*)&A[(size_t)(rowbase + r) * K + cc];
    bf16x8 breg = *(const bf16x8*)&B[(size_t)(colbase + r) * K + cc];
    *(bf16x8*)&As[0][r][cc] = areg;
    *(bf16x8*)&Bs[0][r][cc] = breg;
    __syncthreads();

    for (int kt = 0; kt < K; kt += 32) {
        const int cur = (kt >> 5) & 1, nxt = cur ^ 1;
        const bool more = (kt + 32) < K;
        if (more) {
            areg = *(const bf16x8*)&A[(size_t)(rowbase + r) * K + kt + 32 + cc];
            breg = *(const bf16x8*)&B[(size_t)(colbase + r) * K + kt + 32 + cc];
        }

        bf16x8 af[2], bfr[4];
#pragma unroll
        for (int mt = 0; mt < 2; ++mt)
            af[mt] = *(const bf16x8*)&As[cur][wm + mt * 16 + l15][quad * 8];
#pragma unroll
        for (int nt = 0; nt < 4; ++nt)
            bfr[nt] = *(const bf16x8*)&Bs[cur][wn + nt * 16 + l15][quad * 8];
#pragma unroll
        for (int mt = 0; mt < 2; ++mt)
#pragma unroll
            for (int nt = 0; nt < 4; ++nt)
                acc[mt][nt] = MFMA(af[mt], bfr[nt], acc[mt][nt]);

        if (more) {
            *(bf16x8*)&As[nxt][r][cc] = areg;
            *(bf16x8*)&Bs[nxt][r][cc] = breg;
        }
        __syncthreads();
    }

#pragma unroll
    for (int nt = 0; nt < 4; ++nt) {
        int col  = colbase + wn + nt * 16 + l15;
        float bv = bias[col];
#pragma unroll
        for (int mt = 0; mt < 2; ++mt) {
            int row0 = rowbase + wm + mt * 16 + quad * 4;
#pragma unroll
            for (int rr = 0; rr < 4; ++rr) {
                float v = (acc[mt][nt][rr] + bv) * sc;
                C[(size_t)(row0 + rr) * N + col] = (bf16_t)v;
                if (zi) {
                    int row = row0 + rr;                    // b*S + s
                    int bb = row >> 11, srow = row & (S - 1);
                    int hh = col >> 6,  dd   = col & 63;
                    KTout[(((size_t)bb * H + hh) * DK + dd) * S + srow] = (bf16_t)v;
                }
            }
        }
    }
}

// ---------------------------------------------------------------------------
// Output projection: C[M,N](f32) = Cc[M,K](bf16) * wo[N,K](bf16)^T + bias.
// 64x128 tile, 256 threads (4 waves, 2x2 of 32x64), grid 512 (2 blocks/CU),
// register-prefetch dbuf, 1 barrier/K-step.
// ---------------------------------------------------------------------------
__global__ __launch_bounds__(256) void gemm_obt(
    const bf16_t* __restrict__ A, const bf16_t* __restrict__ B,
    const float* __restrict__ bias, float* __restrict__ C)
{
    constexpr int N = D, K = D;
    __shared__ bf16_t As[2][64][40];
    __shared__ bf16_t Bs[2][128][40];

    const int t    = threadIdx.x;
    const int wave = t >> 6, lane = t & 63;
    const int quad = lane >> 4, l15 = lane & 15;
    const int wm = (wave >> 1) * 32, wn = (wave & 1) * 64;
    const int rowbase = blockIdx.y * 64, colbase = blockIdx.x * 128;
    const int r  = t >> 2;            // 0..63
    const int cc = (t & 3) << 3;

    f32x4 acc[2][4];
#pragma unroll
    for (int i = 0; i < 2; ++i)
#pragma unroll
        for (int j = 0; j < 4; ++j) acc[i][j] = {0.f, 0.f, 0.f, 0.f};

    bf16x8 areg = *(const bf16x8*)&A[(size_t)(rowbase + r) * K + cc];
    bf16x8 breg0 = *(const bf16x8*)&B[(size_t)(colbase + r) * K + cc];
    bf16x8 breg1 = *(const bf16x8*)&B[(size_t)(colbase + 64 + r) * K + cc];
    *(bf16x8*)&As[0][r][cc]      = areg;
    *(bf16x8*)&Bs[0][r][cc]      = breg0;
    *(bf16x8*)&Bs[0][64 + r][cc] = breg1;
    __syncthreads();

    for (int kt = 0; kt < K; kt += 32) {
        const int cur = (kt >> 5) & 1, nxt = cur ^ 1;
        const bool more = (kt + 32) < K;
        if (more) {
            areg  = *(const bf16x8*)&A[(size_t)(rowbase + r) * K + kt + 32 + cc];
            breg0 = *(const bf16x8*)&B[(size_t)(colbase + r) * K + kt + 32 + cc];
            breg1 = *(const bf16x8*)&B[(size_t)(colbase + 64 + r) * K + kt + 32 + cc];
        }

        bf16x8 af[2], bfr[4];
#pragma unroll
        for (int mt = 0; mt < 2; ++mt)
            af[mt] = *(const bf16x8*)&As[cur][wm + mt * 16 + l15][quad * 8];
#pragma unroll
        for (int nt = 0; nt < 4; ++nt)
            bfr[nt] = *(const bf16x8*)&Bs[cur][wn + nt * 16 + l15][quad * 8];
#pragma unroll
        for (int mt = 0; mt < 2; ++mt)
#pragma unroll
            for (int nt = 0; nt < 4; ++nt)
                acc[mt][nt] = MFMA(af[mt], bfr[nt], acc[mt][nt]);

        if (more) {
            *(bf16x8*)&As[nxt][r][cc]      = areg;
            *(bf16x8*)&Bs[nxt][r][cc]      = breg0;
            *(bf16x8*)&Bs[nxt][64 + r][cc] = breg1;
        }
        __syncthreads();
    }

#pragma unroll
    for (int nt = 0; nt < 4; ++nt) {
        int col  = colbase + wn + nt * 16 + l15;
        float bv = bias[col];
#pragma unroll
        for (int mt = 0; mt < 2; ++mt) {
            int row0 = rowbase + wm + mt * 16 + quad * 4;
#pragma unroll
            for (int rr = 0; rr < 4; ++rr)
                C[(size_t)(row0 + rr) * N + col] = acc[mt][nt][rr] + bv;
        }
    }
}

// ---------------------------------------------------------------------------
// Flash attention (causal, V == K), S^T formulation, exp2-domain softmax,
// T13 defer-max, T5 setprio. NEW: the paired q-tiles (qtA, qtB=31-qtA) are
// processed CONCURRENTLY in one j-loop: each K/KT tile is staged once and
// consumed by both (staging/barriers 33 -> 32-qtA, avg 24.5; QK LDS reads
// shared; two independent softmax/PV chains per wave -> intra-wave ILP).
// Compute per block stays balanced (33 tile-computations everywhere).
// ---------------------------------------------------------------------------
__global__ __launch_bounds__(256) void attn_flash(
    const bf16_t* __restrict__ Q, const bf16_t* __restrict__ Km,
    const bf16_t* __restrict__ KT,
    bf16_t* __restrict__ Oc, float* __restrict__ m_ws, float* __restrict__ il_ws)
{
    const int h = blockIdx.y, b = blockIdx.z;
    const int t = threadIdx.x;
    const int wave = t >> 6, lane = t & 63;
    const int quad = lane >> 4, l15 = lane & 15;

    __shared__ bf16_t Ks[2][64][72];   // K tile (QK^T operand), dbuf
    __shared__ bf16_t KTs[2][64][72];  // K^T tile (PV operand), dbuf
    __shared__ bf16_t PA[64][72];      // qtA: Q staging, then per-wave P staging
    __shared__ bf16_t PB[64][72];      // qtB: Q staging, then per-wave P staging

    const int hcol = h * DK;
    const bf16_t* KTh = KT + ((size_t)(b * H + h)) * DK * S;
    const size_t bS = (size_t)b * S;

    const int jr = (t >> 3);
    const int ce = (t & 7) * 8;
    const int iloc = wave * 16 + l15;

    const int qtA = (int)blockIdx.x;        // 0..15
    const int qtB = 31 - qtA;               // 16..31, qtB > qtA always
    const size_t qrowA = bS + (size_t)qtA * 64;
    const size_t qrowB = bS + (size_t)qtB * 64;

    // initial stage: both Q tiles + K/KT tile 0
    bf16x8 qldA[2], qldB[2], kreg[2], ktreg[2];
#pragma unroll
    for (int p = 0; p < 2; ++p) {
        qldA[p]  = *(const bf16x8*)&Q[(qrowA + p * 32 + jr) * D + hcol + ce];
        qldB[p]  = *(const bf16x8*)&Q[(qrowB + p * 32 + jr) * D + hcol + ce];
        kreg[p]  = *(const bf16x8*)&Km[(bS + p * 32 + jr) * D + hcol + ce];
        ktreg[p] = *(const bf16x8*)&KTh[(size_t)(p * 32 + jr) * S + ce];
    }
#pragma unroll
    for (int p = 0; p < 2; ++p) {
        *(bf16x8*)&PA[p * 32 + jr][ce]     = qldA[p];
        *(bf16x8*)&PB[p * 32 + jr][ce]     = qldB[p];
        *(bf16x8*)&Ks[0][p * 32 + jr][ce]  = kreg[p];
        *(bf16x8*)&KTs[0][p * 32 + jr][ce] = ktreg[p];
    }
    __syncthreads();
    const bf16x8 qfA0 = *(const bf16x8*)&PA[wave * 16 + l15][quad * 8];
    const bf16x8 qfA1 = *(const bf16x8*)&PA[wave * 16 + l15][32 + quad * 8];
    const bf16x8 qfB0 = *(const bf16x8*)&PB[wave * 16 + l15][quad * 8];
    const bf16x8 qfB1 = *(const bf16x8*)&PB[wave * 16 + l15][32 + quad * 8];

    f32x4 accA[4], accB[4];
#pragma unroll
    for (int u = 0; u < 4; ++u) { accA[u] = {0.f, 0.f, 0.f, 0.f}; accB[u] = {0.f, 0.f, 0.f, 0.f}; }
    float mA = -1e30f, lA = 0.f, mB = -1e30f, lB = 0.f;

    auto softmax_pv = [&](f32x4 (&sv)[4], int cur, float& m_cur, float& l_cur,
                          f32x4 (&accO)[4], bf16_t (&P)[64][72]) {
        float tm = sv[0][0];
#pragma unroll
        for (int nt = 0; nt < 4; ++nt)
#pragma unroll
            for (int r = 0; r < 4; ++r) tm = fmaxf(tm, sv[nt][r]);
        tm = fmaxf(tm, __shfl_xor(tm, 16));
        tm = fmaxf(tm, __shfl_xor(tm, 32));
        // T13 defer-max: only rescale when the running max grows by >8
        // (exp2 domain -> P bounded by 2^8; stored m/l stay consistent).
        if (__any(tm > m_cur + 8.f)) {
            float m_new = fmaxf(m_cur, tm);
            float alpha = exp2f(m_cur - m_new);
            m_cur = m_new;
            l_cur *= alpha;
            float alpha4[4];
#pragma unroll
            for (int r = 0; r < 4; ++r)
                alpha4[r] = __shfl(alpha, (quad << 4) + quad * 4 + r, 64);
#pragma unroll
            for (int u = 0; u < 4; ++u)
#pragma unroll
                for (int r = 0; r < 4; ++r) accO[u][r] *= alpha4[r];
        }
        float rs = 0.f;
#pragma unroll
        for (int nt = 0; nt < 4; ++nt)
#pragma unroll
            for (int r = 0; r < 4; ++r) {
                float p = exp2f(sv[nt][r] - m_cur);
                sv[nt][r] = p;
                rs += p;
            }
        rs += __shfl_xor(rs, 16);
        rs += __shfl_xor(rs, 32);
        l_cur += rs;

#pragma unroll
        for (int nt = 0; nt < 4; ++nt) {
            bf16x4 pk;
            pk[0] = (bf16_t)sv[nt][0]; pk[1] = (bf16_t)sv[nt][1];
            pk[2] = (bf16_t)sv[nt][2]; pk[3] = (bf16_t)sv[nt][3];
            *(bf16x4*)&P[wave * 16 + l15][nt * 16 + quad * 4] = pk;
        }
        asm volatile("s_waitcnt lgkmcnt(0)" ::: "memory");  // wave-private rows

        bf16x8 pa0 = *(const bf16x8*)&P[wave * 16 + l15][quad * 8];
        bf16x8 pa1 = *(const bf16x8*)&P[wave * 16 + l15][32 + quad * 8];
        __builtin_amdgcn_s_setprio(1);
#pragma unroll
        for (int u = 0; u < 4; ++u) {
            bf16x8 v0 = *(const bf16x8*)&KTs[cur][u * 16 + l15][quad * 8];
            bf16x8 v1 = *(const bf16x8*)&KTs[cur][u * 16 + l15][32 + quad * 8];
            accO[u] = MFMA(pa0, v0, accO[u]);
            accO[u] = MFMA(pa1, v1, accO[u]);
        }
        __builtin_amdgcn_s_setprio(0);
    };

    for (int jt = 0; jt <= qtB; ++jt) {
        const int cur = jt & 1, nxt = cur ^ 1;
        const bool more = jt < qtB;
        if (more) {
#pragma unroll
            for (int p = 0; p < 2; ++p) {
                kreg[p]  = *(const bf16x8*)&Km[(bS + (size_t)(jt + 1) * 64 + p * 32 + jr) * D + hcol + ce];
                ktreg[p] = *(const bf16x8*)&KTh[(size_t)(p * 32 + jr) * S + (size_t)(jt + 1) * 64 + ce];
            }
        }
        const bool actA = jt <= qtA;

        f32x4 svA[4], svB[4];
        __builtin_amdgcn_s_setprio(1);
#pragma unroll
        for (int nt = 0; nt < 4; ++nt) {
            bf16x8 a0 = *(const bf16x8*)&Ks[cur][nt * 16 + l15][quad * 8];
            bf16x8 a1 = *(const bf16x8*)&Ks[cur][nt * 16 + l15][32 + quad * 8];
            f32x4 sb = {0.f, 0.f, 0.f, 0.f};
            sb = MFMA(a0, qfB0, sb);
            sb = MFMA(a1, qfB1, sb);
            svB[nt] = sb;
            if (actA) {
                f32x4 sa = {0.f, 0.f, 0.f, 0.f};
                sa = MFMA(a0, qfA0, sa);
                sa = MFMA(a1, qfA1, sa);
                svA[nt] = sa;
            }
        }
        __builtin_amdgcn_s_setprio(0);

        if (jt == qtB) {
#pragma unroll
            for (int nt = 0; nt < 4; ++nt)
#pragma unroll
                for (int r = 0; r < 4; ++r)
                    if ((nt * 16 + quad * 4 + r) > iloc) svB[nt][r] = -1e30f;
        }
        if (actA && jt == qtA) {
#pragma unroll
            for (int nt = 0; nt < 4; ++nt)
#pragma unroll
                for (int r = 0; r < 4; ++r)
                    if ((nt * 16 + quad * 4 + r) > iloc) svA[nt][r] = -1e30f;
        }

        softmax_pv(svB, cur, mB, lB, accB, PB);
        if (actA) softmax_pv(svA, cur, mA, lA, accA, PA);

        if (more) {
#pragma unroll
            for (int p = 0; p < 2; ++p) {
                *(bf16x8*)&Ks[nxt][p * 32 + jr][ce]  = kreg[p];
                *(bf16x8*)&KTs[nxt][p * 32 + jr][ce] = ktreg[p];
            }
        }
        __syncthreads();
    }

    // epilogue: normalize + write O and stats for both tiles
    {
        float invl = 1.f / lB;
        float invl4[4];
#pragma unroll
        for (int r = 0; r < 4; ++r)
            invl4[r] = __shfl(invl, (quad << 4) + quad * 4 + r, 64);
#pragma unroll
        for (int u = 0; u < 4; ++u)
#pragma unroll
            for (int r = 0; r < 4; ++r)
                Oc[(qrowB + wave * 16 + quad * 4 + r) * D + hcol + u * 16 + l15] =
                    (bf16_t)(accB[u][r] * invl4[r]);
        if (quad == 0) {
            size_t sb = ((size_t)(b * H + h)) * S + (size_t)qtB * 64 + wave * 16 + l15;
            m_ws[sb]  = mB;
            il_ws[sb] = invl;
        }
    }
    {
        float invl = 1.f / lA;
        float invl4[4];
#pragma unroll
        for (int r = 0; r < 4; ++r)
            invl4[r] = __shfl(invl, (quad << 4) + quad * 4 + r, 64);
#pragma unroll
        for (int u = 0; u < 4; ++u)
#pragma unroll
            for (int r = 0; r < 4; ++r)
                Oc[(qrowA + wave * 16 + quad * 4 + r) * D + hcol + u * 16 + l15] =
                    (bf16_t)(accA[u][r] * invl4[r]);
        if (quad == 0) {
            size_t sb = ((size_t)(b * H + h)) * S + (size_t)qtA * 64 + wave * 16 + l15;
            m_ws[sb]  = mA;
            il_ws[sb] = invl;
        }
    }
}

// ---------------------------------------------------------------------------
// Head-summed attention weights (f32): out2[b,i,j] = sum_h exp2(s - m)/l.
// LDS-staged (staging IS the coalescing transpose for MFMA fragments).
// Double-buffered over heads, 1 barrier/head, no setprio (lockstep waves).
// Causal branch hoisted; il factored out (one fma per element per head).
// ---------------------------------------------------------------------------
__global__ __launch_bounds__(256) void attn_wsum(
    const bf16_t* __restrict__ Q, const bf16_t* __restrict__ Km,
    const float* __restrict__ m_ws, const float* __restrict__ il_ws,
    float* __restrict__ out2)
{
    const int jt = blockIdx.x, qt = blockIdx.y, b = blockIdx.z;
    const int t  = threadIdx.x;
    float* tile = out2 + (size_t)b * S * S + (size_t)qt * 64 * S + (size_t)jt * 64;

    if (jt > qt) {
        int r0 = t >> 2, c0 = (t & 3) * 16;
#pragma unroll
        for (int e = 0; e < 16; ++e) tile[(size_t)r0 * S + c0 + e] = 0.f;
        return;
    }

    const int wave = t >> 6, lane = t & 63;
    const int quad = lane >> 4, l15 = lane & 15;
    __shared__ bf16_t Ks[2][64][72];
    __shared__ bf16_t Qs[2][64][72];

    const int jr = (t >> 3), ce = (t & 7) * 8;
    const size_t krow = (size_t)b * S + (size_t)jt * 64;
    const size_t qrow = (size_t)b * S + (size_t)qt * 64;

    f32x4 accs[4];
#pragma unroll
    for (int nt = 0; nt < 4; ++nt) accs[nt] = {0.f, 0.f, 0.f, 0.f};

    bf16x8 kreg[2], qreg[2];
#pragma unroll
    for (int p = 0; p < 2; ++p) {
        kreg[p] = *(const bf16x8*)&Km[(krow + p * 32 + jr) * D + ce];
        qreg[p] = *(const bf16x8*)&Q[(qrow + p * 32 + jr) * D + ce];
    }
#pragma unroll
    for (int p = 0; p < 2; ++p) {
        *(bf16x8*)&Ks[0][p * 32 + jr][ce] = kreg[p];
        *(bf16x8*)&Qs[0][p * 32 + jr][ce] = qreg[p];
    }
    __syncthreads();

    const size_t mlb0 = (size_t)(b * H) * S + (size_t)qt * 64 + wave * 16 + quad * 4;

    if (jt < qt) {
        // off-diagonal: no mask compare/select in the inner loop
        for (int h = 0; h < H; ++h) {
            const int cur = h & 1, nxt = cur ^ 1;
            if (h < H - 1) {
                const int hc = (h + 1) * DK;
#pragma unroll
                for (int p = 0; p < 2; ++p) {
                    kreg[p] = *(const bf16x8*)&Km[(krow + p * 32 + jr) * D + hc + ce];
                    qreg[p] = *(const bf16x8*)&Q[(qrow + p * 32 + jr) * D + hc + ce];
                }
            }

            bf16x8 qf0 = *(const bf16x8*)&Qs[cur][wave * 16 + l15][quad * 8];
            bf16x8 qf1 = *(const bf16x8*)&Qs[cur][wave * 16 + l15][32 + quad * 8];
            f32x4 mr = *(const f32x4*)&m_ws[mlb0 + (size_t)h * S];
            f32x4 il = *(const f32x4*)&il_ws[mlb0 + (size_t)h * S];

#pragma unroll
            for (int nt = 0; nt < 4; ++nt) {
                bf16x8 k0 = *(const bf16x8*)&Ks[cur][nt * 16 + l15][quad * 8];
                bf16x8 k1 = *(const bf16x8*)&Ks[cur][nt * 16 + l15][32 + quad * 8];
                f32x4 a = {0.f, 0.f, 0.f, 0.f};
                a = MFMA(qf0, k0, a);
                a = MFMA(qf1, k1, a);
#pragma unroll
                for (int r = 0; r < 4; ++r)
                    accs[nt][r] = fmaf(exp2f(a[r] - mr[r]), il[r], accs[nt][r]);
            }

            if (h < H - 1) {
#pragma unroll
                for (int p = 0; p < 2; ++p) {
                    *(bf16x8*)&Ks[nxt][p * 32 + jr][ce] = kreg[p];
                    *(bf16x8*)&Qs[nxt][p * 32 + jr][ce] = qreg[p];
                }
            }
            __syncthreads();
        }
    } else {
        // diagonal block: causal mask active
        for (int h = 0; h < H; ++h) {
            const int cur = h & 1, nxt = cur ^ 1;
            if (h < H - 1) {
                const int hc = (h + 1) * DK;
#pragma unroll
                for (int p = 0; p < 2; ++p) {
                    kreg[p] = *(const bf16x8*)&Km[(krow + p * 32 + jr) * D + hc + ce];
                    qreg[p] = *(const bf16x8*)&Q[(qrow + p * 32 + jr) * D + hc + ce];
                }
            }

            bf16x8 qf0 = *(const bf16x8*)&Qs[cur][wave * 16 + l15][quad * 8];
            bf16x8 qf1 = *(const bf16x8*)&Qs[cur][wave * 16 + l15][32 + quad * 8];
            f32x4 mr = *(const f32x4*)&m_ws[mlb0 + (size_t)h * S];
            f32x4 il = *(const f32x4*)&il_ws[mlb0 + (size_t)h * S];

#pragma unroll
            for (int nt = 0; nt < 4; ++nt) {
                bf16x8 k0 = *(const bf16x8*)&Ks[cur][nt * 16 + l15][quad * 8];
                bf16x8 k1 = *(const bf16x8*)&Ks[cur][nt * 16 + l15][32 + quad * 8];
                f32x4 a = {0.f, 0.f, 0.f, 0.f};
                a = MFMA(qf0, k0, a);
                a = MFMA(qf1, k1, a);
#pragma unroll
                for (int r = 0; r < 4; ++r) {
                    int i = wave * 16 + quad * 4 + r;   // row within tile
                    int j = nt * 16 + l15;              // col within tile
                    float p = (j <= i) ? exp2f(a[r] - mr[r]) * il[r] : 0.f;
                    accs[nt][r] += p;
                }
            }

            if (h < H - 1) {
#pragma unroll
                for (int p = 0; p < 2; ++p) {
                    *(bf16x8*)&Ks[nxt][p * 32 + jr][ce] = kreg[p];
                    *(bf16x8*)&Qs[nxt][p * 32 + jr][ce] = qreg[p];
                }
            }
            __syncthreads();
        }
    }

#pragma unroll
    for (int nt = 0; nt < 4; ++nt)
#pragma unroll
        for (int r = 0; r < 4; ++r)
            tile[(size_t)(wave * 16 + quad * 4 + r) * S + nt * 16 + l15] = accs[nt][r];
}

// ---------------------------------------------------------------------------
extern "C" void kernel_launch(void* const* d_in, const int* in_sizes, int n_in,
                              void* d_out, int out_size, void* d_ws, size_t ws_size,
                              hipStream_t stream)
{
    const float* x    = (const float*)d_in[0];
    const float* z    = (const float*)d_in[1];
    // d_in[2] = causal mask (int32 tril) -- structure exploited directly
    const float* wq_w = (const float*)d_in[3];
    const float* wq_b = (const float*)d_in[4];
    const float* wk_w = (const float*)d_in[5];
    const float* wk_b = (const float*)d_in[6];
    // d_in[7], d_in[8] = wv (dead parameter: reference uses wk for V)
    const float* wo_w = (const float*)d_in[9];
    const float* wo_b = (const float*)d_in[10];

    float* out  = (float*)d_out;                    // chunk 0: [B,S,D] f32 (16.78 MB)
    float* out2 = out + (size_t)Bsz * S * D;        // chunk 1: [B,S,S] f32 (32 MB)

    // ws (23.6 MB): stats + bf16 Q (pre-scaled), K, and bf16 weights.
    float*  m_ws  = (float*)d_ws;
    float*  il_ws = m_ws + (size_t)Bsz * H * S;
    bf16_t* Qws   = (bf16_t*)(il_ws + (size_t)Bsz * H * S);
    bf16_t* Kws   = Qws + (size_t)Bsz * S * D;
    bf16_t* wq_bf = Kws + (size_t)Bsz * S * D;
    bf16_t* wk_bf = wq_bf + (size_t)D * D;
    bf16_t* wo_bf = wk_bf + (size_t)D * D;
    // bf16 x,z parked in out chunk 0 (exactly 16.78 MB; dead before gemm_obt
    // overwrites chunk 0 last-but-one).
    bf16_t* xb    = (bf16_t*)out;
    bf16_t* zb    = xb + (size_t)Bsz * S * D;
    // Cc + KT parked in out2 (16.8 of 32 MB; dead before attn_wsum runs last).
    bf16_t* Cc    = (bf16_t*)out2;                  // concat  [B*S, D]
    bf16_t* KTws  = Cc + (size_t)Bsz * S * D;       // K^T [B,H,DK,S]

    constexpr int CVT_BLOCKS = (2 * (Bsz * S * D / 4) + 3 * (D * D / 4)) / 256;
    cvt5<<<dim3(CVT_BLOCKS), dim3(256), 0, stream>>>(
        x, z, wq_w, wk_w, wo_w, xb, zb, wq_bf, wk_bf, wo_bf);
    gemm_qk<<<dim3(D / 128, (Bsz * S) / 128, 2), dim3(512), 0, stream>>>(
        xb, wq_bf, wq_b, Qws, zb, wk_bf, wk_b, Kws, KTws);
    attn_flash<<<dim3(S / 128, H, Bsz), dim3(256), 0, stream>>>(
        Qws, Kws, KTws, Cc, m_ws, il_ws);
    gemm_obt<<<dim3(D / 128, (Bsz * S) / 64, 1), dim3(256), 0, stream>>>(
        Cc, wo_bf, wo_b, out);
    attn_wsum<<<dim3(S / 64, S / 64, Bsz), dim3(256), 0, stream>>>(
        Qws, Kws, m_ws, il_ws, out2);
}

// Round 7
// 271.823 us; speedup vs baseline: 1.0146x; 1.0146x over previous
//
#include <hip/hip_runtime.h>

typedef __bf16 bf16_t;
typedef __bf16 bf16x4 __attribute__((ext_vector_type(4)));
typedef __bf16 bf16x8 __attribute__((ext_vector_type(8)));
typedef float  f32x4  __attribute__((ext_vector_type(4)));

#define MFMA(a, b, c) __builtin_amdgcn_mfma_f32_16x16x32_bf16((a), (b), (c), 0, 0, 0)

static constexpr int Bsz = 2, S = 2048, D = 1024, H = 16, DK = 64;
// softmax runs in exp2 domain: Q is pre-scaled by 0.125 * log2(e)
#define QSCALE 0.18033688011112042f

// Direct global->LDS DMA, 16 B per lane (m97 staging). LDS dest must be
// linear: wave-uniform base + lane*16 (no padding!).
__device__ __forceinline__ void gl16(const bf16_t* g, bf16_t* l)
{
    __builtin_amdgcn_global_load_lds(
        (const __attribute__((address_space(1))) void*)g,
        (__attribute__((address_space(3))) void*)l, 16, 0, 0);
}

// ---------------------------------------------------------------------------
// One-pass f32 -> bf16 conversion of x, z, wq, wk, wo. Each thread converts
// one float4. Segment boundaries are multiples of 64 -> wave-uniform branches.
// ---------------------------------------------------------------------------
__global__ __launch_bounds__(256) void cvt5(
    const float* __restrict__ x, const float* __restrict__ z,
    const float* __restrict__ wq, const float* __restrict__ wk,
    const float* __restrict__ wo,
    bf16_t* __restrict__ xb, bf16_t* __restrict__ zb,
    bf16_t* __restrict__ wqb, bf16_t* __restrict__ wkb, bf16_t* __restrict__ wob)
{
    constexpr int NXZ = Bsz * S * D / 4;   // 1,048,576 float4 chunks
    constexpr int NW  = D * D / 4;         //   262,144
    int i = blockIdx.x * 256 + threadIdx.x;
    const float* s; bf16_t* d; int off;
    if (i < NXZ)                 { s = x;  d = xb;  off = i; }
    else if (i < 2 * NXZ)        { s = z;  d = zb;  off = i - NXZ; }
    else if (i < 2 * NXZ + NW)   { s = wq; d = wqb; off = i - 2 * NXZ; }
    else if (i < 2 * NXZ + 2*NW) { s = wk; d = wkb; off = i - 2 * NXZ - NW; }
    else                         { s = wo; d = wob; off = i - 2 * NXZ - 2 * NW; }
    float4 v = *(const float4*)&s[(size_t)off * 4];
    bf16x4 o;
    o[0] = (bf16_t)v.x; o[1] = (bf16_t)v.y; o[2] = (bf16_t)v.z; o[3] = (bf16_t)v.w;
    *(bf16x4*)&d[(size_t)off * 4] = o;
}

// ---------------------------------------------------------------------------
// Fused Q/K projection, all-bf16 operands. blockIdx.z selects
// (xb,wqb)->Q*QSCALE or (zb,wkb)->K + KT. 128x128 tile, BK=32, 512 threads
// (8 waves, 4x2 of 32x64). NEW: m97-style staging -- global_load_lds 16B/lane
// into LINEAR [128][32] LDS tiles (no VGPR round trip), dbuf, 1 barrier/K-step.
// ---------------------------------------------------------------------------
__global__ __launch_bounds__(512) void gemm_qk(
    const bf16_t* __restrict__ xA, const bf16_t* __restrict__ wqB,
    const float* __restrict__ wqb, bf16_t* __restrict__ Qc,
    const bf16_t* __restrict__ zA, const bf16_t* __restrict__ wkB,
    const float* __restrict__ wkb, bf16_t* __restrict__ Kc,
    bf16_t* __restrict__ KTout)
{
    constexpr int N = D, K = D;
    const int zi = blockIdx.z;
    const bf16_t* A    = zi ? zA  : xA;
    const bf16_t* B    = zi ? wkB : wqB;
    const float*  bias = zi ? wkb : wqb;
    bf16_t*       C    = zi ? Kc  : Qc;
    const float   sc   = zi ? 1.f : QSCALE;   // fold softmax scale + log2e into Q

    __shared__ bf16_t As[2][128][32];   // linear -- required by global_load_lds
    __shared__ bf16_t Bs[2][128][32];

    const int t    = threadIdx.x;
    const int wave = t >> 6, lane = t & 63;
    const int quad = lane >> 4, l15 = lane & 15;
    const int wm = (wave >> 1) * 32, wn = (wave & 1) * 64;
    const int rowbase = blockIdx.y * 128, colbase = blockIdx.x * 128;
    // staging slot: wave w covers rows w*16..w*16+15; lane -> (row, 16B chunk)
    const int srow = wave * 16 + (lane >> 2);
    const int scol = (lane & 3) << 3;

    f32x4 acc[2][4];
#pragma unroll
    for (int i = 0; i < 2; ++i)
#pragma unroll
        for (int j = 0; j < 4; ++j) acc[i][j] = {0.f, 0.f, 0.f, 0.f};

    gl16(&A[(size_t)(rowbase + srow) * K + scol], &As[0][srow][scol]);
    gl16(&B[(size_t)(colbase + srow) * K + scol], &Bs[0][srow][scol]);
    __syncthreads();

    for (int kt = 0; kt < K; kt += 32) {
        const int cur = (kt >> 5) & 1, nxt = cur ^ 1;
        const bool more = (kt + 32) < K;
        if (more) {
            gl16(&A[(size_t)(rowbase + srow) * K + kt + 32 + scol], &As[nxt][srow][scol]);
            gl16(&B[(size_t)(colbase + srow) * K + kt + 32 + scol], &Bs[nxt][srow][scol]);
        }

        bf16x8 af[2], bfr[4];
#pragma unroll
        for (int mt = 0; mt < 2; ++mt)
            af[mt] = *(const bf16x8*)&As[cur][wm + mt * 16 + l15][quad * 8];
#pragma unroll
        for (int nt = 0; nt < 4; ++nt)
            bfr[nt] = *(const bf16x8*)&Bs[cur][wn + nt * 16 + l15][quad * 8];
#pragma unroll
        for (int mt = 0; mt < 2; ++mt)
#pragma unroll
            for (int nt = 0; nt < 4; ++nt)
                acc[mt][nt] = MFMA(af[mt], bfr[nt], acc[mt][nt]);

        __syncthreads();   // drains vmcnt (gload_lds) + lgkmcnt before buffer swap
    }

#pragma unroll
    for (int nt = 0; nt < 4; ++nt) {
        int col  = colbase + wn + nt * 16 + l15;
        float bv = bias[col];
#pragma unroll
        for (int mt = 0; mt < 2; ++mt) {
            int row0 = rowbase + wm + mt * 16 + quad * 4;
#pragma unroll
            for (int rr = 0; rr < 4; ++rr) {
                float v = (acc[mt][nt][rr] + bv) * sc;
                C[(size_t)(row0 + rr) * N + col] = (bf16_t)v;
                if (zi) {
                    int row = row0 + rr;                    // b*S + s
                    int bb = row >> 11, srw = row & (S - 1);
                    int hh = col >> 6,  dd  = col & 63;
                    KTout[(((size_t)bb * H + hh) * DK + dd) * S + srw] = (bf16_t)v;
                }
            }
        }
    }
}

// ---------------------------------------------------------------------------
// Output projection: C[M,N](f32) = Cc[M,K](bf16) * wo[N,K](bf16)^T + bias.
// 64x128 tile, 256 threads (4 waves, 2x2 of 32x64). m97-style global_load_lds
// staging into linear LDS, dbuf, 1 barrier/K-step.
// ---------------------------------------------------------------------------
__global__ __launch_bounds__(256) void gemm_obt(
    const bf16_t* __restrict__ A, const bf16_t* __restrict__ B,
    const float* __restrict__ bias, float* __restrict__ C)
{
    constexpr int N = D, K = D;
    __shared__ bf16_t As[2][64][32];    // linear -- required by global_load_lds
    __shared__ bf16_t Bs[2][128][32];

    const int t    = threadIdx.x;
    const int wave = t >> 6, lane = t & 63;
    const int quad = lane >> 4, l15 = lane & 15;
    const int wm = (wave >> 1) * 32, wn = (wave & 1) * 64;
    const int rowbase = blockIdx.y * 64, colbase = blockIdx.x * 128;
    const int srow = wave * 16 + (lane >> 2);   // 0..63 over 4 waves
    const int scol = (lane & 3) << 3;

    f32x4 acc[2][4];
#pragma unroll
    for (int i = 0; i < 2; ++i)
#pragma unroll
        for (int j = 0; j < 4; ++j) acc[i][j] = {0.f, 0.f, 0.f, 0.f};

    gl16(&A[(size_t)(rowbase + srow) * K + scol],      &As[0][srow][scol]);
    gl16(&B[(size_t)(colbase + srow) * K + scol],      &Bs[0][srow][scol]);
    gl16(&B[(size_t)(colbase + 64 + srow) * K + scol], &Bs[0][64 + srow][scol]);
    __syncthreads();

    for (int kt = 0; kt < K; kt += 32) {
        const int cur = (kt >> 5) & 1, nxt = cur ^ 1;
        const bool more = (kt + 32) < K;
        if (more) {
            gl16(&A[(size_t)(rowbase + srow) * K + kt + 32 + scol],      &As[nxt][srow][scol]);
            gl16(&B[(size_t)(colbase + srow) * K + kt + 32 + scol],      &Bs[nxt][srow][scol]);
            gl16(&B[(size_t)(colbase + 64 + srow) * K + kt + 32 + scol], &Bs[nxt][64 + srow][scol]);
        }

        bf16x8 af[2], bfr[4];
#pragma unroll
        for (int mt = 0; mt < 2; ++mt)
            af[mt] = *(const bf16x8*)&As[cur][wm + mt * 16 + l15][quad * 8];
#pragma unroll
        for (int nt = 0; nt < 4; ++nt)
            bfr[nt] = *(const bf16x8*)&Bs[cur][wn + nt * 16 + l15][quad * 8];
#pragma unroll
        for (int mt = 0; mt < 2; ++mt)
#pragma unroll
            for (int nt = 0; nt < 4; ++nt)
                acc[mt][nt] = MFMA(af[mt], bfr[nt], acc[mt][nt]);

        __syncthreads();
    }

#pragma unroll
    for (int nt = 0; nt < 4; ++nt) {
        int col  = colbase + wn + nt * 16 + l15;
        float bv = bias[col];
#pragma unroll
        for (int mt = 0; mt < 2; ++mt) {
            int row0 = rowbase + wm + mt * 16 + quad * 4;
#pragma unroll
            for (int rr = 0; rr < 4; ++rr)
                C[(size_t)(row0 + rr) * N + col] = acc[mt][nt][rr] + bv;
        }
    }
}

// ---------------------------------------------------------------------------
// Flash attention (causal, V == K), S^T formulation, prefetch-pipelined,
// diagonal tile split out. Q pre-scaled by 0.125*log2e (exp2-domain softmax).
// Paired q-tiles (qt, 31-qt) per block -> 512 balanced blocks, dbuf Ks+KTs,
// 1 barrier/K-step, T13 defer-max, T5 setprio around MFMA clusters.
// (Round-6 lesson: processing the pair CONCURRENTLY regressed -- two
// dependent softmax chains serialize in source order; keep sequential halves.)
// ---------------------------------------------------------------------------
__global__ __launch_bounds__(256) void attn_flash(
    const bf16_t* __restrict__ Q, const bf16_t* __restrict__ Km,
    const bf16_t* __restrict__ KT,
    bf16_t* __restrict__ Oc, float* __restrict__ m_ws, float* __restrict__ il_ws)
{
    const int h = blockIdx.y, b = blockIdx.z;
    const int t = threadIdx.x;
    const int wave = t >> 6, lane = t & 63;
    const int quad = lane >> 4, l15 = lane & 15;

    __shared__ bf16_t Ks[2][64][72];
    __shared__ bf16_t KTs[2][64][72];
    __shared__ bf16_t PQ[64][72];

    const int hcol = h * DK;
    const bf16_t* KTh = KT + ((size_t)(b * H + h)) * DK * S;
    const size_t bS = (size_t)b * S;

    const int jr = (t >> 3);
    const int ce = (t & 7) * 8;
    const int iloc = wave * 16 + l15;

    for (int half = 0; half < 2; ++half) {
        const int qt = half == 0 ? (int)blockIdx.x : 31 - (int)blockIdx.x;
        const size_t qrow0 = bS + (size_t)qt * 64;

        __syncthreads();   // buffers reused across halves
        bf16x8 qld[2], kreg[2], ktreg[2];
#pragma unroll
        for (int p = 0; p < 2; ++p) {
            qld[p]   = *(const bf16x8*)&Q[(qrow0 + p * 32 + jr) * D + hcol + ce];
            kreg[p]  = *(const bf16x8*)&Km[(bS + p * 32 + jr) * D + hcol + ce];
            ktreg[p] = *(const bf16x8*)&KTh[(size_t)(p * 32 + jr) * S + ce];
        }
#pragma unroll
        for (int p = 0; p < 2; ++p) {
            *(bf16x8*)&PQ[p * 32 + jr][ce]     = qld[p];
            *(bf16x8*)&Ks[0][p * 32 + jr][ce]  = kreg[p];
            *(bf16x8*)&KTs[0][p * 32 + jr][ce] = ktreg[p];
        }
        __syncthreads();
        const bf16x8 qf0 = *(const bf16x8*)&PQ[wave * 16 + l15][quad * 8];
        const bf16x8 qf1 = *(const bf16x8*)&PQ[wave * 16 + l15][32 + quad * 8];

        f32x4 accO[4];
#pragma unroll
        for (int u = 0; u < 4; ++u) accO[u] = {0.f, 0.f, 0.f, 0.f};
        float m_cur = -1e30f, l_cur = 0.f;

        auto softmax_pv = [&](f32x4 sv[4], int cur) {
            float tm = sv[0][0];
#pragma unroll
            for (int nt = 0; nt < 4; ++nt)
#pragma unroll
                for (int r = 0; r < 4; ++r) tm = fmaxf(tm, sv[nt][r]);
            tm = fmaxf(tm, __shfl_xor(tm, 16));
            tm = fmaxf(tm, __shfl_xor(tm, 32));
            // T13 defer-max: only rescale when the running max grows by >8
            // (exp2 domain -> P bounded by 2^8; stored m/l stay consistent).
            if (__any(tm > m_cur + 8.f)) {
                float m_new = fmaxf(m_cur, tm);
                float alpha = exp2f(m_cur - m_new);
                m_cur = m_new;
                l_cur *= alpha;
                float alpha4[4];
#pragma unroll
                for (int r = 0; r < 4; ++r)
                    alpha4[r] = __shfl(alpha, (quad << 4) + quad * 4 + r, 64);
#pragma unroll
                for (int u = 0; u < 4; ++u)
#pragma unroll
                    for (int r = 0; r < 4; ++r) accO[u][r] *= alpha4[r];
            }
            float rs = 0.f;
#pragma unroll
            for (int nt = 0; nt < 4; ++nt)
#pragma unroll
                for (int r = 0; r < 4; ++r) {
                    float p = exp2f(sv[nt][r] - m_cur);
                    sv[nt][r] = p;
                    rs += p;
                }
            rs += __shfl_xor(rs, 16);
            rs += __shfl_xor(rs, 32);
            l_cur += rs;

#pragma unroll
            for (int nt = 0; nt < 4; ++nt) {
                bf16x4 pk;
                pk[0] = (bf16_t)sv[nt][0]; pk[1] = (bf16_t)sv[nt][1];
                pk[2] = (bf16_t)sv[nt][2]; pk[3] = (bf16_t)sv[nt][3];
                *(bf16x4*)&PQ[wave * 16 + l15][nt * 16 + quad * 4] = pk;
            }
            asm volatile("s_waitcnt lgkmcnt(0)" ::: "memory");  // wave-private

            bf16x8 pa0 = *(const bf16x8*)&PQ[wave * 16 + l15][quad * 8];
            bf16x8 pa1 = *(const bf16x8*)&PQ[wave * 16 + l15][32 + quad * 8];
            __builtin_amdgcn_s_setprio(1);
#pragma unroll
            for (int u = 0; u < 4; ++u) {
                bf16x8 v0 = *(const bf16x8*)&KTs[cur][u * 16 + l15][quad * 8];
                bf16x8 v1 = *(const bf16x8*)&KTs[cur][u * 16 + l15][32 + quad * 8];
                accO[u] = MFMA(pa0, v0, accO[u]);
                accO[u] = MFMA(pa1, v1, accO[u]);
            }
            __builtin_amdgcn_s_setprio(0);
        };

        for (int jt = 0; jt < qt; ++jt) {
            const int cur = jt & 1, nxt = cur ^ 1;
#pragma unroll
            for (int p = 0; p < 2; ++p) {
                kreg[p]  = *(const bf16x8*)&Km[(bS + (size_t)(jt + 1) * 64 + p * 32 + jr) * D + hcol + ce];
                ktreg[p] = *(const bf16x8*)&KTh[(size_t)(p * 32 + jr) * S + (size_t)(jt + 1) * 64 + ce];
            }

            f32x4 sv[4];
            __builtin_amdgcn_s_setprio(1);
#pragma unroll
            for (int nt = 0; nt < 4; ++nt) {
                bf16x8 a0 = *(const bf16x8*)&Ks[cur][nt * 16 + l15][quad * 8];
                bf16x8 a1 = *(const bf16x8*)&Ks[cur][nt * 16 + l15][32 + quad * 8];
                f32x4 a = {0.f, 0.f, 0.f, 0.f};
                a = MFMA(a0, qf0, a);
                a = MFMA(a1, qf1, a);
                sv[nt] = a;
            }
            __builtin_amdgcn_s_setprio(0);
            softmax_pv(sv, cur);

#pragma unroll
            for (int p = 0; p < 2; ++p) {
                *(bf16x8*)&Ks[nxt][p * 32 + jr][ce]  = kreg[p];
                *(bf16x8*)&KTs[nxt][p * 32 + jr][ce] = ktreg[p];
            }
            __syncthreads();
        }

        {
            const int cur = qt & 1;
            f32x4 sv[4];
            __builtin_amdgcn_s_setprio(1);
#pragma unroll
            for (int nt = 0; nt < 4; ++nt) {
                bf16x8 a0 = *(const bf16x8*)&Ks[cur][nt * 16 + l15][quad * 8];
                bf16x8 a1 = *(const bf16x8*)&Ks[cur][nt * 16 + l15][32 + quad * 8];
                f32x4 a = {0.f, 0.f, 0.f, 0.f};
                a = MFMA(a0, qf0, a);
                a = MFMA(a1, qf1, a);
#pragma unroll
                for (int r = 0; r < 4; ++r)
                    if ((nt * 16 + quad * 4 + r) > iloc) a[r] = -1e30f;
                sv[nt] = a;
            }
            __builtin_amdgcn_s_setprio(0);
            softmax_pv(sv, cur);
        }

        float invl = 1.f / l_cur;
        float invl4[4];
#pragma unroll
        for (int r = 0; r < 4; ++r)
            invl4[r] = __shfl(invl, (quad << 4) + quad * 4 + r, 64);
#pragma unroll
        for (int u = 0; u < 4; ++u)
#pragma unroll
            for (int r = 0; r < 4; ++r)
                Oc[(qrow0 + wave * 16 + quad * 4 + r) * D + hcol + u * 16 + l15] =
                    (bf16_t)(accO[u][r] * invl4[r]);

        if (quad == 0) {
            size_t sb = ((size_t)(b * H + h)) * S + (size_t)qt * 64 + wave * 16 + l15;
            m_ws[sb]  = m_cur;
            il_ws[sb] = invl;
        }
    }
}

// ---------------------------------------------------------------------------
// Head-summed attention weights (f32): out2[b,i,j] = sum_h exp2(s - m)/l.
// LDS-staged (staging IS the coalescing transpose for MFMA fragments).
// Double-buffered over heads, 1 barrier/head, no setprio (lockstep waves).
// Causal branch hoisted; il factored out (one fma per element per head).
// ---------------------------------------------------------------------------
__global__ __launch_bounds__(256) void attn_wsum(
    const bf16_t* __restrict__ Q, const bf16_t* __restrict__ Km,
    const float* __restrict__ m_ws, const float* __restrict__ il_ws,
    float* __restrict__ out2)
{
    const int jt = blockIdx.x, qt = blockIdx.y, b = blockIdx.z;
    const int t  = threadIdx.x;
    float* tile = out2 + (size_t)b * S * S + (size_t)qt * 64 * S + (size_t)jt * 64;

    if (jt > qt) {
        int r0 = t >> 2, c0 = (t & 3) * 16;
#pragma unroll
        for (int e = 0; e < 16; ++e) tile[(size_t)r0 * S + c0 + e] = 0.f;
        return;
    }

    const int wave = t >> 6, lane = t & 63;
    const int quad = lane >> 4, l15 = lane & 15;
    __shared__ bf16_t Ks[2][64][72];
    __shared__ bf16_t Qs[2][64][72];

    const int jr = (t >> 3), ce = (t & 7) * 8;
    const size_t krow = (size_t)b * S + (size_t)jt * 64;
    const size_t qrow = (size_t)b * S + (size_t)qt * 64;

    f32x4 accs[4];
#pragma unroll
    for (int nt = 0; nt < 4; ++nt) accs[nt] = {0.f, 0.f, 0.f, 0.f};

    bf16x8 kreg[2], qreg[2];
#pragma unroll
    for (int p = 0; p < 2; ++p) {
        kreg[p] = *(const bf16x8*)&Km[(krow + p * 32 + jr) * D + ce];
        qreg[p] = *(const bf16x8*)&Q[(qrow + p * 32 + jr) * D + ce];
    }
#pragma unroll
    for (int p = 0; p < 2; ++p) {
        *(bf16x8*)&Ks[0][p * 32 + jr][ce] = kreg[p];
        *(bf16x8*)&Qs[0][p * 32 + jr][ce] = qreg[p];
    }
    __syncthreads();

    const size_t mlb0 = (size_t)(b * H) * S + (size_t)qt * 64 + wave * 16 + quad * 4;

    if (jt < qt) {
        // off-diagonal: no mask compare/select in the inner loop
        for (int h = 0; h < H; ++h) {
            const int cur = h & 1, nxt = cur ^ 1;
            if (h < H - 1) {
                const int hc = (h + 1) * DK;
#pragma unroll
                for (int p = 0; p < 2; ++p) {
                    kreg[p] = *(const bf16x8*)&Km[(krow + p * 32 + jr) * D + hc + ce];
                    qreg[p] = *(const bf16x8*)&Q[(qrow + p * 32 + jr) * D + hc + ce];
                }
            }

            bf16x8 qf0 = *(const bf16x8*)&Qs[cur][wave * 16 + l15][quad * 8];
            bf16x8 qf1 = *(const bf16x8*)&Qs[cur][wave * 16 + l15][32 + quad * 8];
            f32x4 mr = *(const f32x4*)&m_ws[mlb0 + (size_t)h * S];
            f32x4 il = *(const f32x4*)&il_ws[mlb0 + (size_t)h * S];

#pragma unroll
            for (int nt = 0; nt < 4; ++nt) {
                bf16x8 k0 = *(const bf16x8*)&Ks[cur][nt * 16 + l15][quad * 8];
                bf16x8 k1 = *(const bf16x8*)&Ks[cur][nt * 16 + l15][32 + quad * 8];
                f32x4 a = {0.f, 0.f, 0.f, 0.f};
                a = MFMA(qf0, k0, a);
                a = MFMA(qf1, k1, a);
#pragma unroll
                for (int r = 0; r < 4; ++r)
                    accs[nt][r] = fmaf(exp2f(a[r] - mr[r]), il[r], accs[nt][r]);
            }

            if (h < H - 1) {
#pragma unroll
                for (int p = 0; p < 2; ++p) {
                    *(bf16x8*)&Ks[nxt][p * 32 + jr][ce] = kreg[p];
                    *(bf16x8*)&Qs[nxt][p * 32 + jr][ce] = qreg[p];
                }
            }
            __syncthreads();
        }
    } else {
        // diagonal block: causal mask active
        for (int h = 0; h < H; ++h) {
            const int cur = h & 1, nxt = cur ^ 1;
            if (h < H - 1) {
                const int hc = (h + 1) * DK;
#pragma unroll
                for (int p = 0; p < 2; ++p) {
                    kreg[p] = *(const bf16x8*)&Km[(krow + p * 32 + jr) * D + hc + ce];
                    qreg[p] = *(const bf16x8*)&Q[(qrow + p * 32 + jr) * D + hc + ce];
                }
            }

            bf16x8 qf0 = *(const bf16x8*)&Qs[cur][wave * 16 + l15][quad * 8];
            bf16x8 qf1 = *(const bf16x8*)&Qs[cur][wave * 16 + l15][32 + quad * 8];
            f32x4 mr = *(const f32x4*)&m_ws[mlb0 + (size_t)h * S];
            f32x4 il = *(const f32x4*)&il_ws[mlb0 + (size_t)h * S];

#pragma unroll
            for (int nt = 0; nt < 4; ++nt) {
                bf16x8 k0 = *(const bf16x8*)&Ks[cur][nt * 16 + l15][quad * 8];
                bf16x8 k1 = *(const bf16x8*)&Ks[cur][nt * 16 + l15][32 + quad * 8];
                f32x4 a = {0.f, 0.f, 0.f, 0.f};
                a = MFMA(qf0, k0, a);
                a = MFMA(qf1, k1, a);
#pragma unroll
                for (int r = 0; r < 4; ++r) {
                    int i = wave * 16 + quad * 4 + r;   // row within tile
                    int j = nt * 16 + l15;              // col within tile
                    float p = (j <= i) ? exp2f(a[r] - mr[r]) * il[r] : 0.f;
                    accs[nt][r] += p;
                }
            }

            if (h < H - 1) {
#pragma unroll
                for (int p = 0; p < 2; ++p) {
                    *(bf16x8*)&Ks[nxt][p * 32 + jr][ce] = kreg[p];
                    *(bf16x8*)&Qs[nxt][p * 32 + jr][ce] = qreg[p];
                }
            }
            __syncthreads();
        }
    }

#pragma unroll
    for (int nt = 0; nt < 4; ++nt)
#pragma unroll
        for (int r = 0; r < 4; ++r)
            tile[(size_t)(wave * 16 + quad * 4 + r) * S + nt * 16 + l15] = accs[nt][r];
}

// ---------------------------------------------------------------------------
extern "C" void kernel_launch(void* const* d_in, const int* in_sizes, int n_in,
                              void* d_out, int out_size, void* d_ws, size_t ws_size,
                              hipStream_t stream)
{
    const float* x    = (const float*)d_in[0];
    const float* z    = (const float*)d_in[1];
    // d_in[2] = causal mask (int32 tril) -- structure exploited directly
    const float* wq_w = (const float*)d_in[3];
    const float* wq_b = (const float*)d_in[4];
    const float* wk_w = (const float*)d_in[5];
    const float* wk_b = (const float*)d_in[6];
    // d_in[7], d_in[8] = wv (dead parameter: reference uses wk for V)
    const float* wo_w = (const float*)d_in[9];
    const float* wo_b = (const float*)d_in[10];

    float* out  = (float*)d_out;                    // chunk 0: [B,S,D] f32 (16.78 MB)
    float* out2 = out + (size_t)Bsz * S * D;        // chunk 1: [B,S,S] f32 (32 MB)

    // ws (23.6 MB): stats + bf16 Q (pre-scaled), K, and bf16 weights.
    float*  m_ws  = (float*)d_ws;
    float*  il_ws = m_ws + (size_t)Bsz * H * S;
    bf16_t* Qws   = (bf16_t*)(il_ws + (size_t)Bsz * H * S);
    bf16_t* Kws   = Qws + (size_t)Bsz * S * D;
    bf16_t* wq_bf = Kws + (size_t)Bsz * S * D;
    bf16_t* wk_bf = wq_bf + (size_t)D * D;
    bf16_t* wo_bf = wk_bf + (size_t)D * D;
    // bf16 x,z parked in out chunk 0 (exactly 16.78 MB; dead before gemm_obt
    // overwrites chunk 0 last-but-one).
    bf16_t* xb    = (bf16_t*)out;
    bf16_t* zb    = xb + (size_t)Bsz * S * D;
    // Cc + KT parked in out2 (16.8 of 32 MB; dead before attn_wsum runs last).
    bf16_t* Cc    = (bf16_t*)out2;                  // concat  [B*S, D]
    bf16_t* KTws  = Cc + (size_t)Bsz * S * D;       // K^T [B,H,DK,S]

    constexpr int CVT_BLOCKS = (2 * (Bsz * S * D / 4) + 3 * (D * D / 4)) / 256;
    cvt5<<<dim3(CVT_BLOCKS), dim3(256), 0, stream>>>(
        x, z, wq_w, wk_w, wo_w, xb, zb, wq_bf, wk_bf, wo_bf);
    gemm_qk<<<dim3(D / 128, (Bsz * S) / 128, 2), dim3(512), 0, stream>>>(
        xb, wq_bf, wq_b, Qws, zb, wk_bf, wk_b, Kws, KTws);
    attn_flash<<<dim3(S / 128, H, Bsz), dim3(256), 0, stream>>>(
        Qws, Kws, KTws, Cc, m_ws, il_ws);
    gemm_obt<<<dim3(D / 128, (Bsz * S) / 64, 1), dim3(256), 0, stream>>>(
        Cc, wo_bf, wo_b, out);
    attn_wsum<<<dim3(S / 64, S / 64, Bsz), dim3(256), 0, stream>>>(
        Qws, Kws, m_ws, il_ws, out2);
}

// Round 8
// 269.364 us; speedup vs baseline: 1.0239x; 1.0091x over previous
//
#include <hip/hip_runtime.h>

typedef __bf16 bf16_t;
typedef __bf16 bf16x4 __attribute__((ext_vector_type(4)));
typedef __bf16 bf16x8 __attribute__((ext_vector_type(8)));
typedef float  f32x4  __attribute__((ext_vector_type(4)));

#define MFMA(a, b, c) __builtin_amdgcn_mfma_f32_16x16x32_bf16((a), (b), (c), 0, 0, 0)

static constexpr int Bsz = 2, S = 2048, D = 1024, H = 16, DK = 64;
// softmax runs in exp2 domain: Q is pre-scaled by 0.125 * log2(e)
#define QSCALE 0.18033688011112042f

// Direct global->LDS DMA, 16 B per lane (m97 staging). LDS dest must be
// linear: wave-uniform base + lane*16 (no padding!).
__device__ __forceinline__ void gl16(const bf16_t* g, bf16_t* l)
{
    __builtin_amdgcn_global_load_lds(
        (const __attribute__((address_space(1))) void*)g,
        (__attribute__((address_space(3))) void*)l, 16, 0, 0);
}

// ---------------------------------------------------------------------------
// One-pass f32 -> bf16 conversion of x, z, wq, wk, wo. Each thread converts
// one float4. Segment boundaries are multiples of 64 -> wave-uniform branches.
// ---------------------------------------------------------------------------
__global__ __launch_bounds__(256) void cvt5(
    const float* __restrict__ x, const float* __restrict__ z,
    const float* __restrict__ wq, const float* __restrict__ wk,
    const float* __restrict__ wo,
    bf16_t* __restrict__ xb, bf16_t* __restrict__ zb,
    bf16_t* __restrict__ wqb, bf16_t* __restrict__ wkb, bf16_t* __restrict__ wob)
{
    constexpr int NXZ = Bsz * S * D / 4;   // 1,048,576 float4 chunks
    constexpr int NW  = D * D / 4;         //   262,144
    int i = blockIdx.x * 256 + threadIdx.x;
    const float* s; bf16_t* d; int off;
    if (i < NXZ)                 { s = x;  d = xb;  off = i; }
    else if (i < 2 * NXZ)        { s = z;  d = zb;  off = i - NXZ; }
    else if (i < 2 * NXZ + NW)   { s = wq; d = wqb; off = i - 2 * NXZ; }
    else if (i < 2 * NXZ + 2*NW) { s = wk; d = wkb; off = i - 2 * NXZ - NW; }
    else                         { s = wo; d = wob; off = i - 2 * NXZ - 2 * NW; }
    float4 v = *(const float4*)&s[(size_t)off * 4];
    bf16x4 o;
    o[0] = (bf16_t)v.x; o[1] = (bf16_t)v.y; o[2] = (bf16_t)v.z; o[3] = (bf16_t)v.w;
    *(bf16x4*)&d[(size_t)off * 4] = o;
}

// ---------------------------------------------------------------------------
// Fused Q/K projection, all-bf16 operands. blockIdx.z selects
// (xb,wqb)->Q*QSCALE or (zb,wkb)->K + KT. 128x128 tile, BK=32, 512 threads
// (8 waves, 4x2 of 32x64). m97-style staging: global_load_lds 16B/lane into
// LINEAR [128][32] LDS tiles (no VGPR round trip), dbuf, 1 barrier/K-step.
// ---------------------------------------------------------------------------
__global__ __launch_bounds__(512) void gemm_qk(
    const bf16_t* __restrict__ xA, const bf16_t* __restrict__ wqB,
    const float* __restrict__ wqb, bf16_t* __restrict__ Qc,
    const bf16_t* __restrict__ zA, const bf16_t* __restrict__ wkB,
    const float* __restrict__ wkb, bf16_t* __restrict__ Kc,
    bf16_t* __restrict__ KTout)
{
    constexpr int N = D, K = D;
    const int zi = blockIdx.z;
    const bf16_t* A    = zi ? zA  : xA;
    const bf16_t* B    = zi ? wkB : wqB;
    const float*  bias = zi ? wkb : wqb;
    bf16_t*       C    = zi ? Kc  : Qc;
    const float   sc   = zi ? 1.f : QSCALE;   // fold softmax scale + log2e into Q

    __shared__ bf16_t As[2][128][32];   // linear -- required by global_load_lds
    __shared__ bf16_t Bs[2][128][32];

    const int t    = threadIdx.x;
    const int wave = t >> 6, lane = t & 63;
    const int quad = lane >> 4, l15 = lane & 15;
    const int wm = (wave >> 1) * 32, wn = (wave & 1) * 64;
    const int rowbase = blockIdx.y * 128, colbase = blockIdx.x * 128;
    // staging slot: wave w covers rows w*16..w*16+15; lane -> (row, 16B chunk)
    const int srow = wave * 16 + (lane >> 2);
    const int scol = (lane & 3) << 3;

    f32x4 acc[2][4];
#pragma unroll
    for (int i = 0; i < 2; ++i)
#pragma unroll
        for (int j = 0; j < 4; ++j) acc[i][j] = {0.f, 0.f, 0.f, 0.f};

    gl16(&A[(size_t)(rowbase + srow) * K + scol], &As[0][srow][scol]);
    gl16(&B[(size_t)(colbase + srow) * K + scol], &Bs[0][srow][scol]);
    __syncthreads();

    for (int kt = 0; kt < K; kt += 32) {
        const int cur = (kt >> 5) & 1, nxt = cur ^ 1;
        const bool more = (kt + 32) < K;
        if (more) {
            gl16(&A[(size_t)(rowbase + srow) * K + kt + 32 + scol], &As[nxt][srow][scol]);
            gl16(&B[(size_t)(colbase + srow) * K + kt + 32 + scol], &Bs[nxt][srow][scol]);
        }

        bf16x8 af[2], bfr[4];
#pragma unroll
        for (int mt = 0; mt < 2; ++mt)
            af[mt] = *(const bf16x8*)&As[cur][wm + mt * 16 + l15][quad * 8];
#pragma unroll
        for (int nt = 0; nt < 4; ++nt)
            bfr[nt] = *(const bf16x8*)&Bs[cur][wn + nt * 16 + l15][quad * 8];
#pragma unroll
        for (int mt = 0; mt < 2; ++mt)
#pragma unroll
            for (int nt = 0; nt < 4; ++nt)
                acc[mt][nt] = MFMA(af[mt], bfr[nt], acc[mt][nt]);

        __syncthreads();   // drains vmcnt (gload_lds) + lgkmcnt before buffer swap
    }

#pragma unroll
    for (int nt = 0; nt < 4; ++nt) {
        int col  = colbase + wn + nt * 16 + l15;
        float bv = bias[col];
#pragma unroll
        for (int mt = 0; mt < 2; ++mt) {
            int row0 = rowbase + wm + mt * 16 + quad * 4;
#pragma unroll
            for (int rr = 0; rr < 4; ++rr) {
                float v = (acc[mt][nt][rr] + bv) * sc;
                C[(size_t)(row0 + rr) * N + col] = (bf16_t)v;
                if (zi) {
                    int row = row0 + rr;                    // b*S + s
                    int bb = row >> 11, srw = row & (S - 1);
                    int hh = col >> 6,  dd  = col & 63;
                    KTout[(((size_t)bb * H + hh) * DK + dd) * S + srw] = (bf16_t)v;
                }
            }
        }
    }
}

// ---------------------------------------------------------------------------
// Output projection: C[M,N](f32) = Cc[M,K](bf16) * wo[N,K](bf16)^T + bias.
// 64x128 tile, 256 threads (4 waves, 2x2 of 32x64). m97-style global_load_lds
// staging into linear LDS, dbuf, 1 barrier/K-step.
// ---------------------------------------------------------------------------
__global__ __launch_bounds__(256) void gemm_obt(
    const bf16_t* __restrict__ A, const bf16_t* __restrict__ B,
    const float* __restrict__ bias, float* __restrict__ C)
{
    constexpr int N = D, K = D;
    __shared__ bf16_t As[2][64][32];    // linear -- required by global_load_lds
    __shared__ bf16_t Bs[2][128][32];

    const int t    = threadIdx.x;
    const int wave = t >> 6, lane = t & 63;
    const int quad = lane >> 4, l15 = lane & 15;
    const int wm = (wave >> 1) * 32, wn = (wave & 1) * 64;
    const int rowbase = blockIdx.y * 64, colbase = blockIdx.x * 128;
    const int srow = wave * 16 + (lane >> 2);   // 0..63 over 4 waves
    const int scol = (lane & 3) << 3;

    f32x4 acc[2][4];
#pragma unroll
    for (int i = 0; i < 2; ++i)
#pragma unroll
        for (int j = 0; j < 4; ++j) acc[i][j] = {0.f, 0.f, 0.f, 0.f};

    gl16(&A[(size_t)(rowbase + srow) * K + scol],      &As[0][srow][scol]);
    gl16(&B[(size_t)(colbase + srow) * K + scol],      &Bs[0][srow][scol]);
    gl16(&B[(size_t)(colbase + 64 + srow) * K + scol], &Bs[0][64 + srow][scol]);
    __syncthreads();

    for (int kt = 0; kt < K; kt += 32) {
        const int cur = (kt >> 5) & 1, nxt = cur ^ 1;
        const bool more = (kt + 32) < K;
        if (more) {
            gl16(&A[(size_t)(rowbase + srow) * K + kt + 32 + scol],      &As[nxt][srow][scol]);
            gl16(&B[(size_t)(colbase + srow) * K + kt + 32 + scol],      &Bs[nxt][srow][scol]);
            gl16(&B[(size_t)(colbase + 64 + srow) * K + kt + 32 + scol], &Bs[nxt][64 + srow][scol]);
        }

        bf16x8 af[2], bfr[4];
#pragma unroll
        for (int mt = 0; mt < 2; ++mt)
            af[mt] = *(const bf16x8*)&As[cur][wm + mt * 16 + l15][quad * 8];
#pragma unroll
        for (int nt = 0; nt < 4; ++nt)
            bfr[nt] = *(const bf16x8*)&Bs[cur][wn + nt * 16 + l15][quad * 8];
#pragma unroll
        for (int mt = 0; mt < 2; ++mt)
#pragma unroll
            for (int nt = 0; nt < 4; ++nt)
                acc[mt][nt] = MFMA(af[mt], bfr[nt], acc[mt][nt]);

        __syncthreads();
    }

#pragma unroll
    for (int nt = 0; nt < 4; ++nt) {
        int col  = colbase + wn + nt * 16 + l15;
        float bv = bias[col];
#pragma unroll
        for (int mt = 0; mt < 2; ++mt) {
            int row0 = rowbase + wm + mt * 16 + quad * 4;
#pragma unroll
            for (int rr = 0; rr < 4; ++rr)
                C[(size_t)(row0 + rr) * N + col] = acc[mt][nt][rr] + bv;
        }
    }
}

// ---------------------------------------------------------------------------
// Flash attention (causal, V == K), S^T formulation, exp2-domain softmax,
// T13 defer-max, T5 setprio. 512-thread blocks: waves 0-3 own q-tile qtA,
// waves 4-7 own qtB=31-qtA. Each shared K/KT tile is staged ONCE by all 8
// waves and consumed by both groups (r6's sharing gain) while the two
// groups' softmax/PV chains live in DIFFERENT waves -> hardware-interleaved,
// not source-serialized (r6's failure mode). 16 waves/CU (2 blocks x 8).
// Group A skips compute (wave-uniform jt<=qt) past its causal range but
// still stages + barriers.
// ---------------------------------------------------------------------------
__global__ __launch_bounds__(512) void attn_flash(
    const bf16_t* __restrict__ Q, const bf16_t* __restrict__ Km,
    const bf16_t* __restrict__ KT,
    bf16_t* __restrict__ Oc, float* __restrict__ m_ws, float* __restrict__ il_ws)
{
    const int h = blockIdx.y, b = blockIdx.z;
    const int t = threadIdx.x;
    const int wave = t >> 6, lane = t & 63;
    const int quad = lane >> 4, l15 = lane & 15;
    const int grp  = wave >> 2;          // 0 = qtA group, 1 = qtB group
    const int wl   = wave & 3;           // wave index within group

    __shared__ bf16_t Ks[2][64][72];     // K tile (QK^T operand), dbuf, shared
    __shared__ bf16_t KTs[2][64][72];    // K^T tile (PV operand), dbuf, shared
    __shared__ bf16_t PQ[128][72];       // rows 0-63: A Q/P, rows 64-127: B Q/P

    const int hcol = h * DK;
    const bf16_t* KTh = KT + ((size_t)(b * H + h)) * DK * S;
    const size_t bS = (size_t)b * S;

    const int jr = t >> 3;               // 0..63 (512 threads, 8 lanes/row)
    const int ce = (t & 7) * 8;          // 0,8,...,56
    const int iloc = wl * 16 + l15;      // row within the group's 64-row tile
    const int prow = grp * 64 + wl * 16 + l15;  // wave-private P/Q row in PQ

    const int qtA = (int)blockIdx.x;     // 0..15
    const int qtB = 31 - qtA;            // 16..31 (always > qtA)
    const int qt  = grp ? qtB : qtA;
    const size_t qrow0 = bS + (size_t)qt * 64;

    // initial stage: both Q tiles + K/KT tile 0 (all 512 threads cooperate)
    {
        bf16x8 qa  = *(const bf16x8*)&Q[(bS + (size_t)qtA * 64 + jr) * D + hcol + ce];
        bf16x8 qb  = *(const bf16x8*)&Q[(bS + (size_t)qtB * 64 + jr) * D + hcol + ce];
        bf16x8 k0  = *(const bf16x8*)&Km[(bS + jr) * D + hcol + ce];
        bf16x8 kt0 = *(const bf16x8*)&KTh[(size_t)jr * S + ce];
        *(bf16x8*)&PQ[jr][ce]      = qa;
        *(bf16x8*)&PQ[64 + jr][ce] = qb;
        *(bf16x8*)&Ks[0][jr][ce]   = k0;
        *(bf16x8*)&KTs[0][jr][ce]  = kt0;
    }
    __syncthreads();
    // Q fragments (read before any P write to the same rows -- intra-wave
    // ordering guarantees the reads complete before jt=0's softmax stores P).
    const bf16x8 qf0 = *(const bf16x8*)&PQ[prow][quad * 8];
    const bf16x8 qf1 = *(const bf16x8*)&PQ[prow][32 + quad * 8];

    f32x4 accO[4];
#pragma unroll
    for (int u = 0; u < 4; ++u) accO[u] = {0.f, 0.f, 0.f, 0.f};
    float m_cur = -1e30f, l_cur = 0.f;

    auto softmax_pv = [&](f32x4 sv[4], int cur) {
        float tm = sv[0][0];
#pragma unroll
        for (int nt = 0; nt < 4; ++nt)
#pragma unroll
            for (int r = 0; r < 4; ++r) tm = fmaxf(tm, sv[nt][r]);
        tm = fmaxf(tm, __shfl_xor(tm, 16));
        tm = fmaxf(tm, __shfl_xor(tm, 32));
        // T13 defer-max: only rescale when the running max grows by >8
        // (exp2 domain -> P bounded by 2^8; stored m/l stay consistent).
        if (__any(tm > m_cur + 8.f)) {
            float m_new = fmaxf(m_cur, tm);
            float alpha = exp2f(m_cur - m_new);
            m_cur = m_new;
            l_cur *= alpha;
            float alpha4[4];
#pragma unroll
            for (int r = 0; r < 4; ++r)
                alpha4[r] = __shfl(alpha, (quad << 4) + quad * 4 + r, 64);
#pragma unroll
            for (int u = 0; u < 4; ++u)
#pragma unroll
                for (int r = 0; r < 4; ++r) accO[u][r] *= alpha4[r];
        }
        float rs = 0.f;
#pragma unroll
        for (int nt = 0; nt < 4; ++nt)
#pragma unroll
            for (int r = 0; r < 4; ++r) {
                float p = exp2f(sv[nt][r] - m_cur);
                sv[nt][r] = p;
                rs += p;
            }
        rs += __shfl_xor(rs, 16);
        rs += __shfl_xor(rs, 32);
        l_cur += rs;

#pragma unroll
        for (int nt = 0; nt < 4; ++nt) {
            bf16x4 pk;
            pk[0] = (bf16_t)sv[nt][0]; pk[1] = (bf16_t)sv[nt][1];
            pk[2] = (bf16_t)sv[nt][2]; pk[3] = (bf16_t)sv[nt][3];
            *(bf16x4*)&PQ[prow][nt * 16 + quad * 4] = pk;
        }
        asm volatile("s_waitcnt lgkmcnt(0)" ::: "memory");  // wave-private rows

        bf16x8 pa0 = *(const bf16x8*)&PQ[prow][quad * 8];
        bf16x8 pa1 = *(const bf16x8*)&PQ[prow][32 + quad * 8];
        __builtin_amdgcn_s_setprio(1);
#pragma unroll
        for (int u = 0; u < 4; ++u) {
            bf16x8 v0 = *(const bf16x8*)&KTs[cur][u * 16 + l15][quad * 8];
            bf16x8 v1 = *(const bf16x8*)&KTs[cur][u * 16 + l15][32 + quad * 8];
            accO[u] = MFMA(pa0, v0, accO[u]);
            accO[u] = MFMA(pa1, v1, accO[u]);
        }
        __builtin_amdgcn_s_setprio(0);
    };

    for (int jt = 0; jt <= qtB; ++jt) {
        const int cur = jt & 1, nxt = cur ^ 1;
        const bool more = jt < qtB;
        bf16x8 kreg, ktreg;
        if (more) {
            kreg  = *(const bf16x8*)&Km[(bS + (size_t)(jt + 1) * 64 + jr) * D + hcol + ce];
            ktreg = *(const bf16x8*)&KTh[(size_t)jr * S + (size_t)(jt + 1) * 64 + ce];
        }

        if (jt <= qt) {   // wave-uniform: group A idles past its causal range
            f32x4 sv[4];
            __builtin_amdgcn_s_setprio(1);
#pragma unroll
            for (int nt = 0; nt < 4; ++nt) {
                bf16x8 a0 = *(const bf16x8*)&Ks[cur][nt * 16 + l15][quad * 8];
                bf16x8 a1 = *(const bf16x8*)&Ks[cur][nt * 16 + l15][32 + quad * 8];
                f32x4 a = {0.f, 0.f, 0.f, 0.f};
                a = MFMA(a0, qf0, a);
                a = MFMA(a1, qf1, a);
                sv[nt] = a;
            }
            __builtin_amdgcn_s_setprio(0);
            if (jt == qt) {
#pragma unroll
                for (int nt = 0; nt < 4; ++nt)
#pragma unroll
                    for (int r = 0; r < 4; ++r)
                        if ((nt * 16 + quad * 4 + r) > iloc) sv[nt][r] = -1e30f;
            }
            softmax_pv(sv, cur);
        }

        if (more) {
            *(bf16x8*)&Ks[nxt][jr][ce]  = kreg;
            *(bf16x8*)&KTs[nxt][jr][ce] = ktreg;
        }
        __syncthreads();
    }

    // epilogue: normalize + write O and stats for this wave's group tile
    float invl = 1.f / l_cur;
    float invl4[4];
#pragma unroll
    for (int r = 0; r < 4; ++r)
        invl4[r] = __shfl(invl, (quad << 4) + quad * 4 + r, 64);
#pragma unroll
    for (int u = 0; u < 4; ++u)
#pragma unroll
        for (int r = 0; r < 4; ++r)
            Oc[(qrow0 + wl * 16 + quad * 4 + r) * D + hcol + u * 16 + l15] =
                (bf16_t)(accO[u][r] * invl4[r]);

    if (quad == 0) {
        size_t sb = ((size_t)(b * H + h)) * S + (size_t)qt * 64 + wl * 16 + l15;
        m_ws[sb]  = m_cur;
        il_ws[sb] = invl;
    }
}

// ---------------------------------------------------------------------------
// Head-summed attention weights (f32): out2[b,i,j] = sum_h exp2(s - m)/l.
// LDS-staged (staging IS the coalescing transpose for MFMA fragments).
// Double-buffered over heads, 1 barrier/head, no setprio (lockstep waves).
// Causal branch hoisted; il factored out (one fma per element per head).
// ---------------------------------------------------------------------------
__global__ __launch_bounds__(256) void attn_wsum(
    const bf16_t* __restrict__ Q, const bf16_t* __restrict__ Km,
    const float* __restrict__ m_ws, const float* __restrict__ il_ws,
    float* __restrict__ out2)
{
    const int jt = blockIdx.x, qt = blockIdx.y, b = blockIdx.z;
    const int t  = threadIdx.x;
    float* tile = out2 + (size_t)b * S * S + (size_t)qt * 64 * S + (size_t)jt * 64;

    if (jt > qt) {
        int r0 = t >> 2, c0 = (t & 3) * 16;
#pragma unroll
        for (int e = 0; e < 16; ++e) tile[(size_t)r0 * S + c0 + e] = 0.f;
        return;
    }

    const int wave = t >> 6, lane = t & 63;
    const int quad = lane >> 4, l15 = lane & 15;
    __shared__ bf16_t Ks[2][64][72];
    __shared__ bf16_t Qs[2][64][72];

    const int jr = (t >> 3), ce = (t & 7) * 8;
    const size_t krow = (size_t)b * S + (size_t)jt * 64;
    const size_t qrow = (size_t)b * S + (size_t)qt * 64;

    f32x4 accs[4];
#pragma unroll
    for (int nt = 0; nt < 4; ++nt) accs[nt] = {0.f, 0.f, 0.f, 0.f};

    bf16x8 kreg[2], qreg[2];
#pragma unroll
    for (int p = 0; p < 2; ++p) {
        kreg[p] = *(const bf16x8*)&Km[(krow + p * 32 + jr) * D + ce];
        qreg[p] = *(const bf16x8*)&Q[(qrow + p * 32 + jr) * D + ce];
    }
#pragma unroll
    for (int p = 0; p < 2; ++p) {
        *(bf16x8*)&Ks[0][p * 32 + jr][ce] = kreg[p];
        *(bf16x8*)&Qs[0][p * 32 + jr][ce] = qreg[p];
    }
    __syncthreads();

    const size_t mlb0 = (size_t)(b * H) * S + (size_t)qt * 64 + wave * 16 + quad * 4;

    if (jt < qt) {
        // off-diagonal: no mask compare/select in the inner loop
        for (int h = 0; h < H; ++h) {
            const int cur = h & 1, nxt = cur ^ 1;
            if (h < H - 1) {
                const int hc = (h + 1) * DK;
#pragma unroll
                for (int p = 0; p < 2; ++p) {
                    kreg[p] = *(const bf16x8*)&Km[(krow + p * 32 + jr) * D + hc + ce];
                    qreg[p] = *(const bf16x8*)&Q[(qrow + p * 32 + jr) * D + hc + ce];
                }
            }

            bf16x8 qf0 = *(const bf16x8*)&Qs[cur][wave * 16 + l15][quad * 8];
            bf16x8 qf1 = *(const bf16x8*)&Qs[cur][wave * 16 + l15][32 + quad * 8];
            f32x4 mr = *(const f32x4*)&m_ws[mlb0 + (size_t)h * S];
            f32x4 il = *(const f32x4*)&il_ws[mlb0 + (size_t)h * S];

#pragma unroll
            for (int nt = 0; nt < 4; ++nt) {
                bf16x8 k0 = *(const bf16x8*)&Ks[cur][nt * 16 + l15][quad * 8];
                bf16x8 k1 = *(const bf16x8*)&Ks[cur][nt * 16 + l15][32 + quad * 8];
                f32x4 a = {0.f, 0.f, 0.f, 0.f};
                a = MFMA(qf0, k0, a);
                a = MFMA(qf1, k1, a);
#pragma unroll
                for (int r = 0; r < 4; ++r)
                    accs[nt][r] = fmaf(exp2f(a[r] - mr[r]), il[r], accs[nt][r]);
            }

            if (h < H - 1) {
#pragma unroll
                for (int p = 0; p < 2; ++p) {
                    *(bf16x8*)&Ks[nxt][p * 32 + jr][ce] = kreg[p];
                    *(bf16x8*)&Qs[nxt][p * 32 + jr][ce] = qreg[p];
                }
            }
            __syncthreads();
        }
    } else {
        // diagonal block: causal mask active
        for (int h = 0; h < H; ++h) {
            const int cur = h & 1, nxt = cur ^ 1;
            if (h < H - 1) {
                const int hc = (h + 1) * DK;
#pragma unroll
                for (int p = 0; p < 2; ++p) {
                    kreg[p] = *(const bf16x8*)&Km[(krow + p * 32 + jr) * D + hc + ce];
                    qreg[p] = *(const bf16x8*)&Q[(qrow + p * 32 + jr) * D + hc + ce];
                }
            }

            bf16x8 qf0 = *(const bf16x8*)&Qs[cur][wave * 16 + l15][quad * 8];
            bf16x8 qf1 = *(const bf16x8*)&Qs[cur][wave * 16 + l15][32 + quad * 8];
            f32x4 mr = *(const f32x4*)&m_ws[mlb0 + (size_t)h * S];
            f32x4 il = *(const f32x4*)&il_ws[mlb0 + (size_t)h * S];

#pragma unroll
            for (int nt = 0; nt < 4; ++nt) {
                bf16x8 k0 = *(const bf16x8*)&Ks[cur][nt * 16 + l15][quad * 8];
                bf16x8 k1 = *(const bf16x8*)&Ks[cur][nt * 16 + l15][32 + quad * 8];
                f32x4 a = {0.f, 0.f, 0.f, 0.f};
                a = MFMA(qf0, k0, a);
                a = MFMA(qf1, k1, a);
#pragma unroll
                for (int r = 0; r < 4; ++r) {
                    int i = wave * 16 + quad * 4 + r;   // row within tile
                    int j = nt * 16 + l15;              // col within tile
                    float p = (j <= i) ? exp2f(a[r] - mr[r]) * il[r] : 0.f;
                    accs[nt][r] += p;
                }
            }

            if (h < H - 1) {
#pragma unroll
                for (int p = 0; p < 2; ++p) {
                    *(bf16x8*)&Ks[nxt][p * 32 + jr][ce] = kreg[p];
                    *(bf16x8*)&Qs[nxt][p * 32 + jr][ce] = qreg[p];
                }
            }
            __syncthreads();
        }
    }

#pragma unroll
    for (int nt = 0; nt < 4; ++nt)
#pragma unroll
        for (int r = 0; r < 4; ++r)
            tile[(size_t)(wave * 16 + quad * 4 + r) * S + nt * 16 + l15] = accs[nt][r];
}

// ---------------------------------------------------------------------------
extern "C" void kernel_launch(void* const* d_in, const int* in_sizes, int n_in,
                              void* d_out, int out_size, void* d_ws, size_t ws_size,
                              hipStream_t stream)
{
    const float* x    = (const float*)d_in[0];
    const float* z    = (const float*)d_in[1];
    // d_in[2] = causal mask (int32 tril) -- structure exploited directly
    const float* wq_w = (const float*)d_in[3];
    const float* wq_b = (const float*)d_in[4];
    const float* wk_w = (const float*)d_in[5];
    const float* wk_b = (const float*)d_in[6];
    // d_in[7], d_in[8] = wv (dead parameter: reference uses wk for V)
    const float* wo_w = (const float*)d_in[9];
    const float* wo_b = (const float*)d_in[10];

    float* out  = (float*)d_out;                    // chunk 0: [B,S,D] f32 (16.78 MB)
    float* out2 = out + (size_t)Bsz * S * D;        // chunk 1: [B,S,S] f32 (32 MB)

    // ws (23.6 MB): stats + bf16 Q (pre-scaled), K, and bf16 weights.
    float*  m_ws  = (float*)d_ws;
    float*  il_ws = m_ws + (size_t)Bsz * H * S;
    bf16_t* Qws   = (bf16_t*)(il_ws + (size_t)Bsz * H * S);
    bf16_t* Kws   = Qws + (size_t)Bsz * S * D;
    bf16_t* wq_bf = Kws + (size_t)Bsz * S * D;
    bf16_t* wk_bf = wq_bf + (size_t)D * D;
    bf16_t* wo_bf = wk_bf + (size_t)D * D;
    // bf16 x,z parked in out chunk 0 (exactly 16.78 MB; dead before gemm_obt
    // overwrites chunk 0 last-but-one).
    bf16_t* xb    = (bf16_t*)out;
    bf16_t* zb    = xb + (size_t)Bsz * S * D;
    // Cc + KT parked in out2 (16.8 of 32 MB; dead before attn_wsum runs last).
    bf16_t* Cc    = (bf16_t*)out2;                  // concat  [B*S, D]
    bf16_t* KTws  = Cc + (size_t)Bsz * S * D;       // K^T [B,H,DK,S]

    constexpr int CVT_BLOCKS = (2 * (Bsz * S * D / 4) + 3 * (D * D / 4)) / 256;
    cvt5<<<dim3(CVT_BLOCKS), dim3(256), 0, stream>>>(
        x, z, wq_w, wk_w, wo_w, xb, zb, wq_bf, wk_bf, wo_bf);
    gemm_qk<<<dim3(D / 128, (Bsz * S) / 128, 2), dim3(512), 0, stream>>>(
        xb, wq_bf, wq_b, Qws, zb, wk_bf, wk_b, Kws, KTws);
    attn_flash<<<dim3(S / 128, H, Bsz), dim3(512), 0, stream>>>(
        Qws, Kws, KTws, Cc, m_ws, il_ws);
    gemm_obt<<<dim3(D / 128, (Bsz * S) / 64, 1), dim3(256), 0, stream>>>(
        Cc, wo_bf, wo_b, out);
    attn_wsum<<<dim3(S / 64, S / 64, Bsz), dim3(256), 0, stream>>>(
        Qws, Kws, m_ws, il_ws, out2);
}

// Round 9
// 262.685 us; speedup vs baseline: 1.0499x; 1.0254x over previous
//
#include <hip/hip_runtime.h>

typedef __bf16 bf16_t;
typedef __bf16 bf16x4 __attribute__((ext_vector_type(4)));
typedef __bf16 bf16x8 __attribute__((ext_vector_type(8)));
typedef float  f32x4  __attribute__((ext_vector_type(4)));

#define MFMA(a, b, c) __builtin_amdgcn_mfma_f32_16x16x32_bf16((a), (b), (c), 0, 0, 0)

static constexpr int Bsz = 2, S = 2048, D = 1024, H = 16, DK = 64;
// softmax runs in exp2 domain: Q is pre-scaled by 0.125 * log2(e)
#define QSCALE 0.18033688011112042f

// Direct global->LDS DMA, 16 B per lane (m97 staging). LDS dest must be
// linear: wave-uniform base + lane*16 (no padding!).
__device__ __forceinline__ void gl16(const bf16_t* g, bf16_t* l)
{
    __builtin_amdgcn_global_load_lds(
        (const __attribute__((address_space(1))) void*)g,
        (__attribute__((address_space(3))) void*)l, 16, 0, 0);
}

// ---------------------------------------------------------------------------
// One-pass f32 -> bf16 conversion of x, z, wq, wk, wo. Each thread converts
// one float4. Segment boundaries are multiples of 64 -> wave-uniform branches.
// ---------------------------------------------------------------------------
__global__ __launch_bounds__(256) void cvt5(
    const float* __restrict__ x, const float* __restrict__ z,
    const float* __restrict__ wq, const float* __restrict__ wk,
    const float* __restrict__ wo,
    bf16_t* __restrict__ xb, bf16_t* __restrict__ zb,
    bf16_t* __restrict__ wqb, bf16_t* __restrict__ wkb, bf16_t* __restrict__ wob)
{
    constexpr int NXZ = Bsz * S * D / 4;   // 1,048,576 float4 chunks
    constexpr int NW  = D * D / 4;         //   262,144
    int i = blockIdx.x * 256 + threadIdx.x;
    const float* s; bf16_t* d; int off;
    if (i < NXZ)                 { s = x;  d = xb;  off = i; }
    else if (i < 2 * NXZ)        { s = z;  d = zb;  off = i - NXZ; }
    else if (i < 2 * NXZ + NW)   { s = wq; d = wqb; off = i - 2 * NXZ; }
    else if (i < 2 * NXZ + 2*NW) { s = wk; d = wkb; off = i - 2 * NXZ - NW; }
    else                         { s = wo; d = wob; off = i - 2 * NXZ - 2 * NW; }
    float4 v = *(const float4*)&s[(size_t)off * 4];
    bf16x4 o;
    o[0] = (bf16_t)v.x; o[1] = (bf16_t)v.y; o[2] = (bf16_t)v.z; o[3] = (bf16_t)v.w;
    *(bf16x4*)&d[(size_t)off * 4] = o;
}

// ---------------------------------------------------------------------------
// Fused Q/K projection, all-bf16 operands. blockIdx.z selects
// (xb,wqb)->Q*QSCALE or (zb,wkb)->K + KT. 128x128 tile, BK=32, 512 threads
// (8 waves, 4x2 of 32x64). m97-style staging: global_load_lds 16B/lane into
// LINEAR [128][32] LDS tiles (no VGPR round trip), dbuf, 1 barrier/K-step.
// ---------------------------------------------------------------------------
__global__ __launch_bounds__(512) void gemm_qk(
    const bf16_t* __restrict__ xA, const bf16_t* __restrict__ wqB,
    const float* __restrict__ wqb, bf16_t* __restrict__ Qc,
    const bf16_t* __restrict__ zA, const bf16_t* __restrict__ wkB,
    const float* __restrict__ wkb, bf16_t* __restrict__ Kc,
    bf16_t* __restrict__ KTout)
{
    constexpr int N = D, K = D;
    const int zi = blockIdx.z;
    const bf16_t* A    = zi ? zA  : xA;
    const bf16_t* B    = zi ? wkB : wqB;
    const float*  bias = zi ? wkb : wqb;
    bf16_t*       C    = zi ? Kc  : Qc;
    const float   sc   = zi ? 1.f : QSCALE;   // fold softmax scale + log2e into Q

    __shared__ bf16_t As[2][128][32];   // linear -- required by global_load_lds
    __shared__ bf16_t Bs[2][128][32];

    const int t    = threadIdx.x;
    const int wave = t >> 6, lane = t & 63;
    const int quad = lane >> 4, l15 = lane & 15;
    const int wm = (wave >> 1) * 32, wn = (wave & 1) * 64;
    const int rowbase = blockIdx.y * 128, colbase = blockIdx.x * 128;
    // staging slot: wave w covers rows w*16..w*16+15; lane -> (row, 16B chunk)
    const int srow = wave * 16 + (lane >> 2);
    const int scol = (lane & 3) << 3;

    f32x4 acc[2][4];
#pragma unroll
    for (int i = 0; i < 2; ++i)
#pragma unroll
        for (int j = 0; j < 4; ++j) acc[i][j] = {0.f, 0.f, 0.f, 0.f};

    gl16(&A[(size_t)(rowbase + srow) * K + scol], &As[0][srow][scol]);
    gl16(&B[(size_t)(colbase + srow) * K + scol], &Bs[0][srow][scol]);
    __syncthreads();

    for (int kt = 0; kt < K; kt += 32) {
        const int cur = (kt >> 5) & 1, nxt = cur ^ 1;
        const bool more = (kt + 32) < K;
        if (more) {
            gl16(&A[(size_t)(rowbase + srow) * K + kt + 32 + scol], &As[nxt][srow][scol]);
            gl16(&B[(size_t)(colbase + srow) * K + kt + 32 + scol], &Bs[nxt][srow][scol]);
        }

        bf16x8 af[2], bfr[4];
#pragma unroll
        for (int mt = 0; mt < 2; ++mt)
            af[mt] = *(const bf16x8*)&As[cur][wm + mt * 16 + l15][quad * 8];
#pragma unroll
        for (int nt = 0; nt < 4; ++nt)
            bfr[nt] = *(const bf16x8*)&Bs[cur][wn + nt * 16 + l15][quad * 8];
#pragma unroll
        for (int mt = 0; mt < 2; ++mt)
#pragma unroll
            for (int nt = 0; nt < 4; ++nt)
                acc[mt][nt] = MFMA(af[mt], bfr[nt], acc[mt][nt]);

        __syncthreads();   // drains vmcnt (gload_lds) + lgkmcnt before buffer swap
    }

#pragma unroll
    for (int nt = 0; nt < 4; ++nt) {
        int col  = colbase + wn + nt * 16 + l15;
        float bv = bias[col];
#pragma unroll
        for (int mt = 0; mt < 2; ++mt) {
            int row0 = rowbase + wm + mt * 16 + quad * 4;
#pragma unroll
            for (int rr = 0; rr < 4; ++rr) {
                float v = (acc[mt][nt][rr] + bv) * sc;
                C[(size_t)(row0 + rr) * N + col] = (bf16_t)v;
                if (zi) {
                    int row = row0 + rr;                    // b*S + s
                    int bb = row >> 11, srw = row & (S - 1);
                    int hh = col >> 6,  dd  = col & 63;
                    KTout[(((size_t)bb * H + hh) * DK + dd) * S + srw] = (bf16_t)v;
                }
            }
        }
    }
}

// ---------------------------------------------------------------------------
// Output projection: C[M,N](f32) = Cc[M,K](bf16) * wo[N,K](bf16)^T + bias.
// 64x128 tile, 256 threads (4 waves, 2x2 of 32x64). m97-style global_load_lds
// staging into linear LDS, dbuf, 1 barrier/K-step.
// ---------------------------------------------------------------------------
__global__ __launch_bounds__(256) void gemm_obt(
    const bf16_t* __restrict__ A, const bf16_t* __restrict__ B,
    const float* __restrict__ bias, float* __restrict__ C)
{
    constexpr int N = D, K = D;
    __shared__ bf16_t As[2][64][32];    // linear -- required by global_load_lds
    __shared__ bf16_t Bs[2][128][32];

    const int t    = threadIdx.x;
    const int wave = t >> 6, lane = t & 63;
    const int quad = lane >> 4, l15 = lane & 15;
    const int wm = (wave >> 1) * 32, wn = (wave & 1) * 64;
    const int rowbase = blockIdx.y * 64, colbase = blockIdx.x * 128;
    const int srow = wave * 16 + (lane >> 2);   // 0..63 over 4 waves
    const int scol = (lane & 3) << 3;

    f32x4 acc[2][4];
#pragma unroll
    for (int i = 0; i < 2; ++i)
#pragma unroll
        for (int j = 0; j < 4; ++j) acc[i][j] = {0.f, 0.f, 0.f, 0.f};

    gl16(&A[(size_t)(rowbase + srow) * K + scol],      &As[0][srow][scol]);
    gl16(&B[(size_t)(colbase + srow) * K + scol],      &Bs[0][srow][scol]);
    gl16(&B[(size_t)(colbase + 64 + srow) * K + scol], &Bs[0][64 + srow][scol]);
    __syncthreads();

    for (int kt = 0; kt < K; kt += 32) {
        const int cur = (kt >> 5) & 1, nxt = cur ^ 1;
        const bool more = (kt + 32) < K;
        if (more) {
            gl16(&A[(size_t)(rowbase + srow) * K + kt + 32 + scol],      &As[nxt][srow][scol]);
            gl16(&B[(size_t)(colbase + srow) * K + kt + 32 + scol],      &Bs[nxt][srow][scol]);
            gl16(&B[(size_t)(colbase + 64 + srow) * K + kt + 32 + scol], &Bs[nxt][64 + srow][scol]);
        }

        bf16x8 af[2], bfr[4];
#pragma unroll
        for (int mt = 0; mt < 2; ++mt)
            af[mt] = *(const bf16x8*)&As[cur][wm + mt * 16 + l15][quad * 8];
#pragma unroll
        for (int nt = 0; nt < 4; ++nt)
            bfr[nt] = *(const bf16x8*)&Bs[cur][wn + nt * 16 + l15][quad * 8];
#pragma unroll
        for (int mt = 0; mt < 2; ++mt)
#pragma unroll
            for (int nt = 0; nt < 4; ++nt)
                acc[mt][nt] = MFMA(af[mt], bfr[nt], acc[mt][nt]);

        __syncthreads();
    }

#pragma unroll
    for (int nt = 0; nt < 4; ++nt) {
        int col  = colbase + wn + nt * 16 + l15;
        float bv = bias[col];
#pragma unroll
        for (int mt = 0; mt < 2; ++mt) {
            int row0 = rowbase + wm + mt * 16 + quad * 4;
#pragma unroll
            for (int rr = 0; rr < 4; ++rr)
                C[(size_t)(row0 + rr) * N + col] = acc[mt][nt][rr] + bv;
        }
    }
}

// ---------------------------------------------------------------------------
// Flash attention (causal, V == K), S^T formulation, exp2-domain softmax,
// T13 defer-max, T5 setprio. 512-thread blocks: waves 0-3 own q-tile qtA,
// waves 4-7 own qtB=31-qtA; shared K/KT staging (r8). NEW (r9): slimmed
// softmax chain -- (a) l-sum cross-quad reduce deferred to the epilogue
// (per-lane partials; rescale alpha is row-uniform so partials stay exact);
// (b) tm cross-quad reduce moved INSIDE the rare rescale branch (per-lane
// partial max triggers __any identically: row max > m+8 iff some lane's
// partial > m+8). Removes 4 dependent cross-lane shuffles per iteration.
// ---------------------------------------------------------------------------
__global__ __launch_bounds__(512) void attn_flash(
    const bf16_t* __restrict__ Q, const bf16_t* __restrict__ Km,
    const bf16_t* __restrict__ KT,
    bf16_t* __restrict__ Oc, float* __restrict__ m_ws, float* __restrict__ il_ws)
{
    const int h = blockIdx.y, b = blockIdx.z;
    const int t = threadIdx.x;
    const int wave = t >> 6, lane = t & 63;
    const int quad = lane >> 4, l15 = lane & 15;
    const int grp  = wave >> 2;          // 0 = qtA group, 1 = qtB group
    const int wl   = wave & 3;           // wave index within group

    __shared__ bf16_t Ks[2][64][72];     // K tile (QK^T operand), dbuf, shared
    __shared__ bf16_t KTs[2][64][72];    // K^T tile (PV operand), dbuf, shared
    __shared__ bf16_t PQ[128][72];       // rows 0-63: A Q/P, rows 64-127: B Q/P

    const int hcol = h * DK;
    const bf16_t* KTh = KT + ((size_t)(b * H + h)) * DK * S;
    const size_t bS = (size_t)b * S;

    const int jr = t >> 3;               // 0..63 (512 threads, 8 lanes/row)
    const int ce = (t & 7) * 8;          // 0,8,...,56
    const int iloc = wl * 16 + l15;      // row within the group's 64-row tile
    const int prow = grp * 64 + wl * 16 + l15;  // wave-private P/Q row in PQ

    const int qtA = (int)blockIdx.x;     // 0..15
    const int qtB = 31 - qtA;            // 16..31 (always > qtA)
    const int qt  = grp ? qtB : qtA;
    const size_t qrow0 = bS + (size_t)qt * 64;

    // initial stage: both Q tiles + K/KT tile 0 (all 512 threads cooperate)
    {
        bf16x8 qa  = *(const bf16x8*)&Q[(bS + (size_t)qtA * 64 + jr) * D + hcol + ce];
        bf16x8 qb  = *(const bf16x8*)&Q[(bS + (size_t)qtB * 64 + jr) * D + hcol + ce];
        bf16x8 k0  = *(const bf16x8*)&Km[(bS + jr) * D + hcol + ce];
        bf16x8 kt0 = *(const bf16x8*)&KTh[(size_t)jr * S + ce];
        *(bf16x8*)&PQ[jr][ce]      = qa;
        *(bf16x8*)&PQ[64 + jr][ce] = qb;
        *(bf16x8*)&Ks[0][jr][ce]   = k0;
        *(bf16x8*)&KTs[0][jr][ce]  = kt0;
    }
    __syncthreads();
    // Q fragments (read before any P write to the same rows -- intra-wave
    // ordering guarantees the reads complete before jt=0's softmax stores P).
    const bf16x8 qf0 = *(const bf16x8*)&PQ[prow][quad * 8];
    const bf16x8 qf1 = *(const bf16x8*)&PQ[prow][32 + quad * 8];

    f32x4 accO[4];
#pragma unroll
    for (int u = 0; u < 4; ++u) accO[u] = {0.f, 0.f, 0.f, 0.f};
    float m_cur = -1e30f, l_cur = 0.f;   // l_cur: PER-LANE partial (quad slice)

    auto softmax_pv = [&](f32x4 sv[4], int cur) {
        // per-lane partial max over this lane's 16 j-values
        float tm = sv[0][0];
#pragma unroll
        for (int nt = 0; nt < 4; ++nt)
#pragma unroll
            for (int r = 0; r < 4; ++r) tm = fmaxf(tm, sv[nt][r]);
        // T13 defer-max, trigger on PER-LANE partial (equivalent to row test:
        // __any spans all 64 lanes -> fires iff some row max exceeds m+8).
        if (__any(tm > m_cur + 8.f)) {
            tm = fmaxf(tm, __shfl_xor(tm, 16));     // row reduce, rare path only
            tm = fmaxf(tm, __shfl_xor(tm, 32));
            float m_new = fmaxf(m_cur, tm);
            float alpha = exp2f(m_cur - m_new);     // row-uniform
            m_cur = m_new;
            l_cur *= alpha;                         // scales per-lane partial exactly
            float alpha4[4];
#pragma unroll
            for (int r = 0; r < 4; ++r)
                alpha4[r] = __shfl(alpha, (quad << 4) + quad * 4 + r, 64);
#pragma unroll
            for (int u = 0; u < 4; ++u)
#pragma unroll
                for (int r = 0; r < 4; ++r) accO[u][r] *= alpha4[r];
        }
        float rs = 0.f;
#pragma unroll
        for (int nt = 0; nt < 4; ++nt)
#pragma unroll
            for (int r = 0; r < 4; ++r) {
                float p = exp2f(sv[nt][r] - m_cur);
                sv[nt][r] = p;
                rs += p;
            }
        l_cur += rs;                                // partial; reduced in epilogue

#pragma unroll
        for (int nt = 0; nt < 4; ++nt) {
            bf16x4 pk;
            pk[0] = (bf16_t)sv[nt][0]; pk[1] = (bf16_t)sv[nt][1];
            pk[2] = (bf16_t)sv[nt][2]; pk[3] = (bf16_t)sv[nt][3];
            *(bf16x4*)&PQ[prow][nt * 16 + quad * 4] = pk;
        }
        asm volatile("s_waitcnt lgkmcnt(0)" ::: "memory");  // wave-private rows

        bf16x8 pa0 = *(const bf16x8*)&PQ[prow][quad * 8];
        bf16x8 pa1 = *(const bf16x8*)&PQ[prow][32 + quad * 8];
        __builtin_amdgcn_s_setprio(1);
#pragma unroll
        for (int u = 0; u < 4; ++u) {
            bf16x8 v0 = *(const bf16x8*)&KTs[cur][u * 16 + l15][quad * 8];
            bf16x8 v1 = *(const bf16x8*)&KTs[cur][u * 16 + l15][32 + quad * 8];
            accO[u] = MFMA(pa0, v0, accO[u]);
            accO[u] = MFMA(pa1, v1, accO[u]);
        }
        __builtin_amdgcn_s_setprio(0);
    };

    for (int jt = 0; jt <= qtB; ++jt) {
        const int cur = jt & 1, nxt = cur ^ 1;
        const bool more = jt < qtB;
        bf16x8 kreg, ktreg;
        if (more) {
            kreg  = *(const bf16x8*)&Km[(bS + (size_t)(jt + 1) * 64 + jr) * D + hcol + ce];
            ktreg = *(const bf16x8*)&KTh[(size_t)jr * S + (size_t)(jt + 1) * 64 + ce];
        }

        if (jt <= qt) {   // wave-uniform: group A idles past its causal range
            f32x4 sv[4];
            __builtin_amdgcn_s_setprio(1);
#pragma unroll
            for (int nt = 0; nt < 4; ++nt) {
                bf16x8 a0 = *(const bf16x8*)&Ks[cur][nt * 16 + l15][quad * 8];
                bf16x8 a1 = *(const bf16x8*)&Ks[cur][nt * 16 + l15][32 + quad * 8];
                f32x4 a = {0.f, 0.f, 0.f, 0.f};
                a = MFMA(a0, qf0, a);
                a = MFMA(a1, qf1, a);
                sv[nt] = a;
            }
            __builtin_amdgcn_s_setprio(0);
            if (jt == qt) {
#pragma unroll
                for (int nt = 0; nt < 4; ++nt)
#pragma unroll
                    for (int r = 0; r < 4; ++r)
                        if ((nt * 16 + quad * 4 + r) > iloc) sv[nt][r] = -1e30f;
            }
            softmax_pv(sv, cur);
        }

        if (more) {
            *(bf16x8*)&Ks[nxt][jr][ce]  = kreg;
            *(bf16x8*)&KTs[nxt][jr][ce] = ktreg;
        }
        __syncthreads();
    }

    // epilogue: complete the deferred l reduce, normalize + write O and stats
    l_cur += __shfl_xor(l_cur, 16);
    l_cur += __shfl_xor(l_cur, 32);
    float invl = 1.f / l_cur;
    float invl4[4];
#pragma unroll
    for (int r = 0; r < 4; ++r)
        invl4[r] = __shfl(invl, (quad << 4) + quad * 4 + r, 64);
#pragma unroll
    for (int u = 0; u < 4; ++u)
#pragma unroll
        for (int r = 0; r < 4; ++r)
            Oc[(qrow0 + wl * 16 + quad * 4 + r) * D + hcol + u * 16 + l15] =
                (bf16_t)(accO[u][r] * invl4[r]);

    if (quad == 0) {
        size_t sb = ((size_t)(b * H + h)) * S + (size_t)qt * 64 + wl * 16 + l15;
        m_ws[sb]  = m_cur;
        il_ws[sb] = invl;
    }
}

// ---------------------------------------------------------------------------
// Head-summed attention weights (f32): out2[b,i,j] = sum_h exp2(s - m)/l.
// LDS-staged (staging IS the coalescing transpose for MFMA fragments).
// Double-buffered over heads, 1 barrier/head, no setprio (lockstep waves).
// Causal branch hoisted; il factored out (one fma per element per head).
// ---------------------------------------------------------------------------
__global__ __launch_bounds__(256) void attn_wsum(
    const bf16_t* __restrict__ Q, const bf16_t* __restrict__ Km,
    const float* __restrict__ m_ws, const float* __restrict__ il_ws,
    float* __restrict__ out2)
{
    const int jt = blockIdx.x, qt = blockIdx.y, b = blockIdx.z;
    const int t  = threadIdx.x;
    float* tile = out2 + (size_t)b * S * S + (size_t)qt * 64 * S + (size_t)jt * 64;

    if (jt > qt) {
        int r0 = t >> 2, c0 = (t & 3) * 16;
#pragma unroll
        for (int e = 0; e < 16; ++e) tile[(size_t)r0 * S + c0 + e] = 0.f;
        return;
    }

    const int wave = t >> 6, lane = t & 63;
    const int quad = lane >> 4, l15 = lane & 15;
    __shared__ bf16_t Ks[2][64][72];
    __shared__ bf16_t Qs[2][64][72];

    const int jr = (t >> 3), ce = (t & 7) * 8;
    const size_t krow = (size_t)b * S + (size_t)jt * 64;
    const size_t qrow = (size_t)b * S + (size_t)qt * 64;

    f32x4 accs[4];
#pragma unroll
    for (int nt = 0; nt < 4; ++nt) accs[nt] = {0.f, 0.f, 0.f, 0.f};

    bf16x8 kreg[2], qreg[2];
#pragma unroll
    for (int p = 0; p < 2; ++p) {
        kreg[p] = *(const bf16x8*)&Km[(krow + p * 32 + jr) * D + ce];
        qreg[p] = *(const bf16x8*)&Q[(qrow + p * 32 + jr) * D + ce];
    }
#pragma unroll
    for (int p = 0; p < 2; ++p) {
        *(bf16x8*)&Ks[0][p * 32 + jr][ce] = kreg[p];
        *(bf16x8*)&Qs[0][p * 32 + jr][ce] = qreg[p];
    }
    __syncthreads();

    const size_t mlb0 = (size_t)(b * H) * S + (size_t)qt * 64 + wave * 16 + quad * 4;

    if (jt < qt) {
        // off-diagonal: no mask compare/select in the inner loop
        for (int h = 0; h < H; ++h) {
            const int cur = h & 1, nxt = cur ^ 1;
            if (h < H - 1) {
                const int hc = (h + 1) * DK;
#pragma unroll
                for (int p = 0; p < 2; ++p) {
                    kreg[p] = *(const bf16x8*)&Km[(krow + p * 32 + jr) * D + hc + ce];
                    qreg[p] = *(const bf16x8*)&Q[(qrow + p * 32 + jr) * D + hc + ce];
                }
            }

            bf16x8 qf0 = *(const bf16x8*)&Qs[cur][wave * 16 + l15][quad * 8];
            bf16x8 qf1 = *(const bf16x8*)&Qs[cur][wave * 16 + l15][32 + quad * 8];
            f32x4 mr = *(const f32x4*)&m_ws[mlb0 + (size_t)h * S];
            f32x4 il = *(const f32x4*)&il_ws[mlb0 + (size_t)h * S];

#pragma unroll
            for (int nt = 0; nt < 4; ++nt) {
                bf16x8 k0 = *(const bf16x8*)&Ks[cur][nt * 16 + l15][quad * 8];
                bf16x8 k1 = *(const bf16x8*)&Ks[cur][nt * 16 + l15][32 + quad * 8];
                f32x4 a = {0.f, 0.f, 0.f, 0.f};
                a = MFMA(qf0, k0, a);
                a = MFMA(qf1, k1, a);
#pragma unroll
                for (int r = 0; r < 4; ++r)
                    accs[nt][r] = fmaf(exp2f(a[r] - mr[r]), il[r], accs[nt][r]);
            }

            if (h < H - 1) {
#pragma unroll
                for (int p = 0; p < 2; ++p) {
                    *(bf16x8*)&Ks[nxt][p * 32 + jr][ce] = kreg[p];
                    *(bf16x8*)&Qs[nxt][p * 32 + jr][ce] = qreg[p];
                }
            }
            __syncthreads();
        }
    } else {
        // diagonal block: causal mask active
        for (int h = 0; h < H; ++h) {
            const int cur = h & 1, nxt = cur ^ 1;
            if (h < H - 1) {
                const int hc = (h + 1) * DK;
#pragma unroll
                for (int p = 0; p < 2; ++p) {
                    kreg[p] = *(const bf16x8*)&Km[(krow + p * 32 + jr) * D + hc + ce];
                    qreg[p] = *(const bf16x8*)&Q[(qrow + p * 32 + jr) * D + hc + ce];
                }
            }

            bf16x8 qf0 = *(const bf16x8*)&Qs[cur][wave * 16 + l15][quad * 8];
            bf16x8 qf1 = *(const bf16x8*)&Qs[cur][wave * 16 + l15][32 + quad * 8];
            f32x4 mr = *(const f32x4*)&m_ws[mlb0 + (size_t)h * S];
            f32x4 il = *(const f32x4*)&il_ws[mlb0 + (size_t)h * S];

#pragma unroll
            for (int nt = 0; nt < 4; ++nt) {
                bf16x8 k0 = *(const bf16x8*)&Ks[cur][nt * 16 + l15][quad * 8];
                bf16x8 k1 = *(const bf16x8*)&Ks[cur][nt * 16 + l15][32 + quad * 8];
                f32x4 a = {0.f, 0.f, 0.f, 0.f};
                a = MFMA(qf0, k0, a);
                a = MFMA(qf1, k1, a);
#pragma unroll
                for (int r = 0; r < 4; ++r) {
                    int i = wave * 16 + quad * 4 + r;   // row within tile
                    int j = nt * 16 + l15;              // col within tile
                    float p = (j <= i) ? exp2f(a[r] - mr[r]) * il[r] : 0.f;
                    accs[nt][r] += p;
                }
            }

            if (h < H - 1) {
#pragma unroll
                for (int p = 0; p < 2; ++p) {
                    *(bf16x8*)&Ks[nxt][p * 32 + jr][ce] = kreg[p];
                    *(bf16x8*)&Qs[nxt][p * 32 + jr][ce] = qreg[p];
                }
            }
            __syncthreads();
        }
    }

#pragma unroll
    for (int nt = 0; nt < 4; ++nt)
#pragma unroll
        for (int r = 0; r < 4; ++r)
            tile[(size_t)(wave * 16 + quad * 4 + r) * S + nt * 16 + l15] = accs[nt][r];
}

// ---------------------------------------------------------------------------
extern "C" void kernel_launch(void* const* d_in, const int* in_sizes, int n_in,
                              void* d_out, int out_size, void* d_ws, size_t ws_size,
                              hipStream_t stream)
{
    const float* x    = (const float*)d_in[0];
    const float* z    = (const float*)d_in[1];
    // d_in[2] = causal mask (int32 tril) -- structure exploited directly
    const float* wq_w = (const float*)d_in[3];
    const float* wq_b = (const float*)d_in[4];
    const float* wk_w = (const float*)d_in[5];
    const float* wk_b = (const float*)d_in[6];
    // d_in[7], d_in[8] = wv (dead parameter: reference uses wk for V)
    const float* wo_w = (const float*)d_in[9];
    const float* wo_b = (const float*)d_in[10];

    float* out  = (float*)d_out;                    // chunk 0: [B,S,D] f32 (16.78 MB)
    float* out2 = out + (size_t)Bsz * S * D;        // chunk 1: [B,S,S] f32 (32 MB)

    // ws (23.6 MB): stats + bf16 Q (pre-scaled), K, and bf16 weights.
    float*  m_ws  = (float*)d_ws;
    float*  il_ws = m_ws + (size_t)Bsz * H * S;
    bf16_t* Qws   = (bf16_t*)(il_ws + (size_t)Bsz * H * S);
    bf16_t* Kws   = Qws + (size_t)Bsz * S * D;
    bf16_t* wq_bf = Kws + (size_t)Bsz * S * D;
    bf16_t* wk_bf = wq_bf + (size_t)D * D;
    bf16_t* wo_bf = wk_bf + (size_t)D * D;
    // bf16 x,z parked in out chunk 0 (exactly 16.78 MB; dead before gemm_obt
    // overwrites chunk 0 last-but-one).
    bf16_t* xb    = (bf16_t*)out;
    bf16_t* zb    = xb + (size_t)Bsz * S * D;
    // Cc + KT parked in out2 (16.8 of 32 MB; dead before attn_wsum runs last).
    bf16_t* Cc    = (bf16_t*)out2;                  // concat  [B*S, D]
    bf16_t* KTws  = Cc + (size_t)Bsz * S * D;       // K^T [B,H,DK,S]

    constexpr int CVT_BLOCKS = (2 * (Bsz * S * D / 4) + 3 * (D * D / 4)) / 256;
    cvt5<<<dim3(CVT_BLOCKS), dim3(256), 0, stream>>>(
        x, z, wq_w, wk_w, wo_w, xb, zb, wq_bf, wk_bf, wo_bf);
    gemm_qk<<<dim3(D / 128, (Bsz * S) / 128, 2), dim3(512), 0, stream>>>(
        xb, wq_bf, wq_b, Qws, zb, wk_bf, wk_b, Kws, KTws);
    attn_flash<<<dim3(S / 128, H, Bsz), dim3(512), 0, stream>>>(
        Qws, Kws, KTws, Cc, m_ws, il_ws);
    gemm_obt<<<dim3(D / 128, (Bsz * S) / 64, 1), dim3(256), 0, stream>>>(
        Cc, wo_bf, wo_b, out);
    attn_wsum<<<dim3(S / 64, S / 64, Bsz), dim3(256), 0, stream>>>(
        Qws, Kws, m_ws, il_ws, out2);
}